// Round 5
// baseline (783.888 us; speedup 1.0000x reference)
//
#include <hip/hip_runtime.h>
#include <hip/hip_bf16.h>

typedef __attribute__((ext_vector_type(8))) short short8;
typedef __attribute__((ext_vector_type(4))) float f32x4;

#define B_ 8
#define C_ 64
#define H_ 256
#define W_ 256
#define HW_ 65536
#define K_ 10
#define NS1 24
#define NS2 18

static __device__ __forceinline__ unsigned short f2bf(float f) {
    __hip_bfloat16 hb = __float2bfloat16(f);
    return *(unsigned short*)&hb;
}
static __device__ __forceinline__ float bf2f(unsigned short u) {
    unsigned v = ((unsigned)u) << 16;
    float f;
    __builtin_memcpy(&f, &v, 4);
    return f;
}

// ---------------------------------------------------------------------------
// Fragment-ordered, gamma-folded, expert-mixed weights + biases (unchanged).
// W4_1: [b][24 steps][4 of][64 lane][8] bf16 (0..17 conv taps, 18..23 1x1)
// W4_2: [b][18 steps][4][64][8] bf16
// ---------------------------------------------------------------------------
__global__ void k_combine(const float* __restrict__ attn, const float* __restrict__ gamma,
                          const float* __restrict__ w1, const float* __restrict__ b1,
                          const float* __restrict__ w2, const float* __restrict__ b2,
                          const float* __restrict__ w16, const float* __restrict__ w168,
                          const float* __restrict__ w88,
                          unsigned short* __restrict__ W4_1, unsigned short* __restrict__ W4_2,
                          float* __restrict__ bias1, float* __restrict__ bias2) {
    const int N1 = B_ * NS1 * 2048;
    const int N2 = B_ * NS2 * 2048;
    int gid = blockIdx.x * 256 + threadIdx.x;
    if (gid < N1) {
        int b = gid / (NS1 * 2048);
        int r = gid - b * (NS1 * 2048);
        int s = r >> 11;
        int r2 = r & 2047;
        int of = r2 >> 9, l = (r2 >> 3) & 63, j = r2 & 7;
        int o = of * 16 + (l & 15);
        int g = l >> 4;
        float val;
        if (s < 18) {
            int t = s >> 1, h = s & 1;
            int c = h * 32 + g * 8 + j;
            float acc = 0.f;
            #pragma unroll
            for (int k = 0; k < K_; ++k)
                acc += attn[b * K_ + k] * w2[((size_t)(k * 64 + o) * 64 + c) * 9 + t];
            val = acc * gamma[b * 64 + o];
        } else {
            int e = s - 18;
            int m = e >> 1, h = e & 1;
            int c = h * 32 + g * 8 + j;
            const float* wm = (m == 0) ? w16 : (m == 1 ? w168 : w88);
            val = wm[o * 64 + c];
        }
        W4_1[gid] = f2bf(val);
    } else if (gid < N1 + N2) {
        int gid2 = gid - N1;
        int b = gid2 / (NS2 * 2048);
        int r = gid2 - b * (NS2 * 2048);
        int s = r >> 11;
        int r2 = r & 2047;
        int of = r2 >> 9, l = (r2 >> 3) & 63, j = r2 & 7;
        int o = of * 16 + (l & 15);
        int g = l >> 4;
        int t = s >> 1, h = s & 1;
        int c = h * 32 + g * 8 + j;
        float acc = 0.f;
        #pragma unroll
        for (int k = 0; k < K_; ++k)
            acc += attn[b * K_ + k] * w1[((size_t)(k * 64 + o) * 64 + c) * 9 + t];
        W4_2[gid2] = f2bf(acc * gamma[b * 64 + o]);
    } else if (gid < N1 + N2 + 1024) {
        int id2 = gid - N1 - N2;
        int b = id2 >> 7;
        int rest = id2 & 127;
        int o = rest >> 1;
        int which = rest & 1;
        const float* bb = which ? b1 : b2;
        float acc = 0.f;
        #pragma unroll
        for (int k = 0; k < K_; ++k) acc += attn[b * K_ + k] * bb[k * 64 + o];
        float v = acc * gamma[b * 64 + o];
        if (which) bias2[b * 64 + o] = v; else bias1[b * 64 + o] = v;
    }
}

// ---------------------------------------------------------------------------
// x [b][64][HW] f32  ->  X1 [b][HW][64] bf16 (unpadded, R3 version)
// ---------------------------------------------------------------------------
__global__ __launch_bounds__(256) void k_prep(const float* __restrict__ x,
                                              unsigned short* __restrict__ X1) {
    __shared__ float ls[64][65];
    const int b = blockIdx.y;
    const int px0 = blockIdx.x * 64;
    const int t = threadIdx.x;
    for (int e = t; e < 4096; e += 256) {
        int ch = e >> 6, px = e & 63;
        ls[ch][px] = x[((size_t)b * 64 + ch) * HW_ + px0 + px];
    }
    __syncthreads();
    for (int e = t; e < 4096; e += 256) {
        int ch = e & 63, px = e >> 6;
        X1[((size_t)b * HW_ + px0 + px) * 64 + ch] = f2bf(ls[ch][px]);
    }
}

// ---------------------------------------------------------------------------
// Fused conv1+conv2 with rolling 3-row LDS rings (T never touches HBM).
// Band: 64 w interior x 16 rows. 4 waves = (mw: M-split) x (ow: of-pair).
// xring: 3 x [68 px][64 c] bf16 (px 0 <-> image col w0-2)
// tring: 3 x [66 px][64 o] bf16 (px 0 <-> image col w0-1)
// ---------------------------------------------------------------------------
__global__ __launch_bounds__(256, 3) void k_fused(
    const unsigned short* __restrict__ X1,   // [b][HW][64] bf16
    const float* __restrict__ x_res,         // [b][64][HW] f32
    const float* __restrict__ par,           // [b][3][HW] f32
    const unsigned short* __restrict__ W1,   // [b][24][4][64][8]
    const unsigned short* __restrict__ W2,   // [b][18][4][64][8]
    const float* __restrict__ bias_s1,
    const float* __restrict__ bias_s2,
    float* __restrict__ outp)                // [b][64][HW] f32
{
    __shared__ short xr_[3 * 4352];          // 3 x 8704 B
    __shared__ short trng[3 * 4224];         // 3 x 8448 B
    __shared__ float parb[3][66];            // par row (m, pxT)

    const int tid = threadIdx.x;
    const int l = tid & 63, wv = tid >> 6;
    const int ln15 = l & 15, g = l >> 4;
    const int mw = wv & 1, ow = wv >> 1;
    const int b = blockIdx.y;
    const int cb = blockIdx.x & 3, rb = blockIdx.x >> 2;
    const int w0 = cb * 64, r0 = rb * 16;

    const unsigned short* Xb  = X1 + (size_t)b * HW_ * 64;
    const unsigned short* W1b = W1 + (size_t)b * NS1 * 2048;
    const unsigned short* W2b = W2 + (size_t)b * NS2 * 2048;

    float bi1[2], bi2[2];
    #pragma unroll
    for (int jj = 0; jj < 2; ++jj) {
        int o = (2 * ow + jj) * 16 + ln15;
        bi1[jj] = bias_s1[b * 64 + o];
        bi2[jj] = bias_s2[b * 64 + o];
    }

    auto stage_x = [&](int rs, int sl) {
        #pragma unroll
        for (int it = 0; it < 3; ++it) {
            int tau = tid + it * 256;
            if (tau < 544) {
                int px = tau >> 3, s = tau & 7;
                int col = w0 - 2 + px;
                short8 v = {0, 0, 0, 0, 0, 0, 0, 0};
                if ((unsigned)rs < 256u && (unsigned)col < 256u) {
                    int cbk = s ^ (px & 7);
                    v = *(const short8*)(Xb + ((size_t)(rs * 256 + col)) * 64 + cbk * 8);
                }
                *(short8*)((char*)xr_ + sl * 8704 + tau * 16) = v;
            }
        }
    };

    // prologue: x rows r0-2, r0-1
    stage_x(r0 - 2, (r0 + 1) % 3);
    stage_x(r0 - 1, (r0 + 2) % 3);

    int tw = (r0 + 2) % 3;   // slot of T row tr (tr starts at r0-1)
    for (int tr = r0 - 1; tr <= r0 + 16; ++tr) {
        const int twp1 = (tw == 2) ? 0 : tw + 1;
        const int twp2 = (twp1 == 2) ? 0 : twp1 + 1;

        // ---- S: stage x row tr+1 (slot (tr+1)%3 == twp1) + par row tr
        stage_x(tr + 1, twp1);
        if (tid < 198) {
            int m = tid / 66, px = tid - m * 66;
            int col = w0 - 1 + px;
            float v = 0.f;
            if ((unsigned)tr < 256u && (unsigned)col < 256u)
                v = par[((size_t)(b * 3 + m)) * HW_ + tr * 256 + col];
            parb[m][px] = v;
        }
        __syncthreads();

        // ---- C1: stage1 computes T row tr into tring slot tw
        if ((unsigned)tr < 256u) {
            const char* xrow[3] = {             // dh=0,1,2 -> x rows tr-1,tr,tr+1
                (const char*)xr_ + twp2 * 8704,
                (const char*)xr_ + tw   * 8704,
                (const char*)xr_ + twp1 * 8704 };

            f32x4 acc1[3][2];
            #pragma unroll
            for (int ff = 0; ff < 3; ++ff)
                #pragma unroll
                for (int jj = 0; jj < 2; ++jj)
                    acc1[ff][jj] = (f32x4){0.f, 0.f, 0.f, 0.f};

            // conv taps: 18 steps
            #pragma unroll
            for (int s = 0; s < 18; ++s) {
                const int dh = s / 6, dw = (s / 2) % 3, h = s & 1;
                #pragma unroll
                for (int ff = 0; ff < 3; ++ff) {
                    if (mw && ff >= 2) continue;
                    int f = mw ? 3 + ff : ff;
                    int idx = 16 * f + ln15 + dw;
                    idx = idx > 67 ? 67 : idx;
                    short8 af = *(const short8*)(xrow[dh] + idx * 128 +
                                 ((((h << 2) | g) ^ (idx & 7)) << 4));
                    #pragma unroll
                    for (int jj = 0; jj < 2; ++jj) {
                        int of = 2 * ow + jj;
                        short8 bf = *(const short8*)(W1b + (s * 4 + of) * 512 + l * 8);
                        acc1[ff][jj] = __builtin_amdgcn_mfma_f32_16x16x32_bf16(
                            af, bf, acc1[ff][jj], 0, 0, 0);
                    }
                }
            }
            // par-scaled 1x1 experts: 6 steps (center tap)
            #pragma unroll
            for (int s = 18; s < 24; ++s) {
                const int m = (s - 18) >> 1, h = s & 1;
                #pragma unroll
                for (int ff = 0; ff < 3; ++ff) {
                    if (mw && ff >= 2) continue;
                    int f = mw ? 3 + ff : ff;
                    int idxT = 16 * f + ln15;
                    int idxX = idxT + 1 > 67 ? 67 : idxT + 1;
                    float pv = parb[m][idxT > 65 ? 65 : idxT];
                    short8 af = *(const short8*)(xrow[1] + idxX * 128 +
                                 ((((h << 2) | g) ^ (idxX & 7)) << 4));
                    short8 sa;
                    #pragma unroll
                    for (int j = 0; j < 8; ++j)
                        sa[j] = (short)f2bf(bf2f((unsigned short)af[j]) * pv);
                    #pragma unroll
                    for (int jj = 0; jj < 2; ++jj) {
                        int of = 2 * ow + jj;
                        short8 bf = *(const short8*)(W1b + (s * 4 + of) * 512 + l * 8);
                        acc1[ff][jj] = __builtin_amdgcn_mfma_f32_16x16x32_bf16(
                            sa, bf, acc1[ff][jj], 0, 0, 0);
                    }
                }
            }
            // bias + relu + write T row into tring (masked)
            char* tdst = (char*)trng + tw * 8448;
            #pragma unroll
            for (int ff = 0; ff < 3; ++ff) {
                if (mw && ff >= 2) continue;
                int f = mw ? 3 + ff : ff;
                #pragma unroll
                for (int jj = 0; jj < 2; ++jj) {
                    int o = (2 * ow + jj) * 16 + ln15;
                    #pragma unroll
                    for (int q = 0; q < 4; ++q) {
                        int pxT = 16 * f + 4 * g + q;
                        if (pxT < 66) {
                            int col = w0 - 1 + pxT;
                            float v = acc1[ff][jj][q] + bi1[jj];
                            v = fmaxf(v, 0.f);
                            if ((unsigned)col >= 256u) v = 0.f;
                            *(short*)(tdst + pxT * 128 +
                                      ((((o >> 3) ^ (pxT & 7))) << 4) + (o & 7) * 2) =
                                (short)f2bf(v);
                        }
                    }
                }
            }
        } else {
            // zero-fill T ring slot (conv zero-pad rows)
            char* tdst = (char*)trng + tw * 8448;
            #pragma unroll
            for (int it = 0; it < 3; ++it) {
                int tau = tid + it * 256;
                if (tau < 528)
                    *(short8*)(tdst + tau * 16) = (short8){0, 0, 0, 0, 0, 0, 0, 0};
            }
        }
        __syncthreads();

        // ---- C2: stage2 output row r = tr-1
        if (tr > r0) {
            const int r = tr - 1;
            const char* trow[3] = {             // dh=0,1,2 -> T rows r-1,r,r+1
                (const char*)trng + twp1 * 8448,
                (const char*)trng + twp2 * 8448,
                (const char*)trng + tw   * 8448 };

            f32x4 acc2[2][2];
            #pragma unroll
            for (int ff = 0; ff < 2; ++ff)
                #pragma unroll
                for (int jj = 0; jj < 2; ++jj)
                    acc2[ff][jj] = (f32x4){0.f, 0.f, 0.f, 0.f};

            #pragma unroll
            for (int s = 0; s < 18; ++s) {
                const int dh = s / 6, dw = (s / 2) % 3, h = s & 1;
                #pragma unroll
                for (int ff = 0; ff < 2; ++ff) {
                    int f = 2 * mw + ff;
                    int idx = 16 * f + ln15 + dw;   // <= 65, always in-range
                    short8 af = *(const short8*)(trow[dh] + idx * 128 +
                                 ((((h << 2) | g) ^ (idx & 7)) << 4));
                    #pragma unroll
                    for (int jj = 0; jj < 2; ++jj) {
                        int of = 2 * ow + jj;
                        short8 bf = *(const short8*)(W2b + (s * 4 + of) * 512 + l * 8);
                        acc2[ff][jj] = __builtin_amdgcn_mfma_f32_16x16x32_bf16(
                            af, bf, acc2[ff][jj], 0, 0, 0);
                    }
                }
            }
            // epilogue: residual add + write out (f32x4)
            #pragma unroll
            for (int ff = 0; ff < 2; ++ff) {
                int f = 2 * mw + ff;
                #pragma unroll
                for (int jj = 0; jj < 2; ++jj) {
                    int o = (2 * ow + jj) * 16 + ln15;
                    size_t idx = ((size_t)(b * 64 + o)) * HW_ + r * 256 + w0 + 16 * f + 4 * g;
                    f32x4 xv = *(const f32x4*)(x_res + idx);
                    f32x4 ov;
                    #pragma unroll
                    for (int q = 0; q < 4; ++q)
                        ov[q] = xv[q] + acc2[ff][jj][q] + bi2[jj];
                    *(f32x4*)(outp + idx) = ov;
                }
            }
        }
        __syncthreads();
        tw = twp1;
    }
}

extern "C" void kernel_launch(void* const* d_in, const int* in_sizes, int n_in,
                              void* d_out, int out_size, void* d_ws, size_t ws_size,
                              hipStream_t stream) {
    const float* x     = (const float*)d_in[0];
    const float* attn  = (const float*)d_in[1];
    const float* gamma = (const float*)d_in[2];
    const float* par   = (const float*)d_in[3];
    const float* w1    = (const float*)d_in[4];
    const float* b1    = (const float*)d_in[5];
    const float* w2    = (const float*)d_in[6];
    const float* b2    = (const float*)d_in[7];
    const float* w16   = (const float*)d_in[8];
    const float* w168  = (const float*)d_in[9];
    const float* w88   = (const float*)d_in[10];
    float* out = (float*)d_out;

    char* w = (char*)d_ws;
    unsigned short* W4_1 = (unsigned short*)w;                    // 786432 B
    unsigned short* W4_2 = (unsigned short*)(w + 786432);         // 589824 B
    float* bias1 = (float*)(w + 1376256);                         // 2048 B (from b2, stage1)
    float* bias2 = (float*)(w + 1378304);                         // 2048 B (from b1, stage2)
    unsigned short* X1 = (unsigned short*)(w + 1380352);          // 67108864 B

    k_combine<<<dim3(2692), dim3(256), 0, stream>>>(attn, gamma, w1, b1, w2, b2,
                                                    w16, w168, w88, W4_1, W4_2, bias1, bias2);
    k_prep<<<dim3(1024, 8), dim3(256), 0, stream>>>(x, X1);

    k_fused<<<dim3(64, 8), dim3(256), 0, stream>>>(X1, x, par, W4_1, W4_2,
                                                   bias1, bias2, out);
}

// Round 6
// 372.342 us; speedup vs baseline: 2.1053x; 2.1053x over previous
//
#include <hip/hip_runtime.h>
#include <hip/hip_bf16.h>

typedef __attribute__((ext_vector_type(8))) short short8;
typedef __attribute__((ext_vector_type(4))) float f32x4;

#define B_ 8
#define C_ 64
#define H_ 256
#define W_ 256
#define HW_ 65536
#define K_ 10
#define NS1 24
#define NS2 18
#define HP_ 258
#define WP_ 258
#define PXP_ (HP_*WP_)

static __device__ __forceinline__ unsigned short f2bf(float f) {
    __hip_bfloat16 hb = __float2bfloat16(f);
    return *(unsigned short*)&hb;
}
static __device__ __forceinline__ float bf2f(unsigned short u) {
    unsigned v = ((unsigned)u) << 16;
    float f;
    __builtin_memcpy(&f, &v, 4);
    return f;
}

// ---------------------------------------------------------------------------
// Fragment-ordered, gamma-folded, expert-mixed weights + biases.
// W4_1: [b][24 steps][4 of][64 lane][8] bf16 (0..17 conv taps, 18..23 1x1)
// W4_2: [b][18 steps][4][64][8] bf16
// ---------------------------------------------------------------------------
__global__ void k_combine(const float* __restrict__ attn, const float* __restrict__ gamma,
                          const float* __restrict__ w1, const float* __restrict__ b1,
                          const float* __restrict__ w2, const float* __restrict__ b2,
                          const float* __restrict__ w16, const float* __restrict__ w168,
                          const float* __restrict__ w88,
                          unsigned short* __restrict__ W4_1, unsigned short* __restrict__ W4_2,
                          float* __restrict__ bias1, float* __restrict__ bias2) {
    const int N1 = B_ * NS1 * 2048;
    const int N2 = B_ * NS2 * 2048;
    int gid = blockIdx.x * 256 + threadIdx.x;
    if (gid < N1) {
        int b = gid / (NS1 * 2048);
        int r = gid - b * (NS1 * 2048);
        int s = r >> 11;
        int r2 = r & 2047;
        int of = r2 >> 9, l = (r2 >> 3) & 63, j = r2 & 7;
        int o = of * 16 + (l & 15);
        int g = l >> 4;
        float val;
        if (s < 18) {
            int t = s >> 1, h = s & 1;
            int c = h * 32 + g * 8 + j;
            float acc = 0.f;
            #pragma unroll
            for (int k = 0; k < K_; ++k)
                acc += attn[b * K_ + k] * w2[((size_t)(k * 64 + o) * 64 + c) * 9 + t];
            val = acc * gamma[b * 64 + o];
        } else {
            int e = s - 18;
            int m = e >> 1, h = e & 1;
            int c = h * 32 + g * 8 + j;
            const float* wm = (m == 0) ? w16 : (m == 1 ? w168 : w88);
            val = wm[o * 64 + c];
        }
        W4_1[gid] = f2bf(val);
    } else if (gid < N1 + N2) {
        int gid2 = gid - N1;
        int b = gid2 / (NS2 * 2048);
        int r = gid2 - b * (NS2 * 2048);
        int s = r >> 11;
        int r2 = r & 2047;
        int of = r2 >> 9, l = (r2 >> 3) & 63, j = r2 & 7;
        int o = of * 16 + (l & 15);
        int g = l >> 4;
        int t = s >> 1, h = s & 1;
        int c = h * 32 + g * 8 + j;
        float acc = 0.f;
        #pragma unroll
        for (int k = 0; k < K_; ++k)
            acc += attn[b * K_ + k] * w1[((size_t)(k * 64 + o) * 64 + c) * 9 + t];
        W4_2[gid2] = f2bf(acc * gamma[b * 64 + o]);
    } else if (gid < N1 + N2 + 1024) {
        int id2 = gid - N1 - N2;
        int b = id2 >> 7;
        int rest = id2 & 127;
        int o = rest >> 1;
        int which = rest & 1;
        const float* bb = which ? b1 : b2;
        float acc = 0.f;
        #pragma unroll
        for (int k = 0; k < K_; ++k) acc += attn[b * K_ + k] * bb[k * 64 + o];
        float v = acc * gamma[b * 64 + o];
        if (which) bias2[b * 64 + o] = v; else bias1[b * 64 + o] = v;
    }
}

// ---------------------------------------------------------------------------
// Zero halo borders of the padded X1p / Tp buffers.
// ---------------------------------------------------------------------------
__global__ void k_border(unsigned short* __restrict__ X1p, unsigned short* __restrict__ Tp) {
    int gid = blockIdx.x * 256 + threadIdx.x;
    if (gid >= 2 * B_ * 1028 * 8) return;
    int chunk = gid & 7;
    int rest = gid >> 3;
    int p = rest % 1028;
    int rb = rest / 1028;
    int buf = rb & 1, b = rb >> 1;
    int row, col;
    if (p < 258) { row = 0; col = p; }
    else if (p < 516) { row = 257; col = p - 258; }
    else if (p < 772) { row = p - 516 + 1; col = 0; }
    else { row = p - 772 + 1; col = 257; }
    unsigned short* base = (buf ? Tp : X1p) +
        ((size_t)b * PXP_ + (size_t)row * WP_ + col) * 64 + chunk * 8;
    *(short8*)base = (short8){0, 0, 0, 0, 0, 0, 0, 0};
}

// ---------------------------------------------------------------------------
// x [b][64][HW] f32  ->  X1p [b][258][258][64] bf16 (interior only)
// ---------------------------------------------------------------------------
__global__ __launch_bounds__(256) void k_prep(const float* __restrict__ x,
                                              unsigned short* __restrict__ X1p) {
    __shared__ float ls[64][65];
    const int b = blockIdx.y;
    const int px0 = blockIdx.x * 64;
    const int row = px0 >> 8;
    const int col0 = px0 & 255;
    const int t = threadIdx.x;
    for (int e = t; e < 4096; e += 256) {
        int ch = e >> 6, px = e & 63;
        ls[ch][px] = x[((size_t)b * 64 + ch) * HW_ + px0 + px];
    }
    __syncthreads();
    unsigned short* dst = X1p + ((size_t)b * PXP_ + (size_t)(row + 1) * WP_ + col0 + 1) * 64;
    for (int e = t; e < 4096; e += 256) {
        int ch = e & 63, px = e >> 6;
        dst[(size_t)px * 64 + ch] = f2bf(ls[ch][px]);
    }
}

// ---- B frags: fragment-ordered global, 1KB coalesced per of
static __device__ __forceinline__ void load_b4(const unsigned short* __restrict__ Wb,
                                               int l, int s, short8* d) {
    const unsigned short* wp = Wb + s * 2048 + l * 8;
    d[0] = *(const short8*)(wp);
    d[1] = *(const short8*)(wp + 512);
    d[2] = *(const short8*)(wp + 1024);
    d[3] = *(const short8*)(wp + 1536);
}

// ---------------------------------------------------------------------------
// Implicit-GEMM conv3x3 via MFMA, A-operand DIRECT from padded global
// (L1/L2-served; no LDS staging, no barriers in the K-loop).
// Tile: 4 img-rows x 64 w x 64 o, 4 waves (one per row).
// ---------------------------------------------------------------------------
template<int STAGE>
__global__ __launch_bounds__(256, 3) void k_conv(
    const unsigned short* __restrict__ Xp,    // [b][258][258][64] bf16 padded
    const float* __restrict__ x_res,          // stage2 residual [b][o][px]
    const float* __restrict__ par,            // stage1 [b][3][HW]
    const unsigned short* __restrict__ W4,    // [b][NS][4][64][8] bf16
    const float* __restrict__ bias,           // [b][64]
    unsigned short* __restrict__ Tp,          // stage1 out [b][258][258][64] bf16
    float* __restrict__ Fout)                 // stage2 out [b][64][HW] f32
{
    const int tid = threadIdx.x;
    const int l = tid & 63;
    const int wv = tid >> 6;
    const int b = blockIdx.y;
    const int rblk = blockIdx.x >> 2;         // 0..63
    const int cblk = blockIdx.x & 3;          // 0..3
    const int gh0 = rblk * 4, w0 = cblk * 64;
    const int ln15 = l & 15, g = l >> 4;

    const unsigned short* Xs = Xp + (size_t)b * PXP_ * 64;
    const unsigned short* Wb = W4 + (size_t)b * ((STAGE == 1 ? NS1 : NS2) * 2048);

    f32x4 acc[4][4];
    #pragma unroll
    for (int mf = 0; mf < 4; ++mf)
        #pragma unroll
        for (int of = 0; of < 4; ++of)
            acc[mf][of] = (f32x4){0.f, 0.f, 0.f, 0.f};

    // A-frag loader: all call sites have compile-time s (fully unrolled loops)
    auto aload = [&](int s, short8* d) {
        const int t = s >> 1, h = s & 1;
        const int dh = t / 3, dw = t - 3 * dh;
        #pragma unroll
        for (int mf = 0; mf < 4; ++mf) {
            size_t off = ((size_t)(gh0 + wv + dh) * WP_ + (w0 + 16 * mf + ln15 + dw)) * 64
                         + (h * 4 + g) * 8;
            d[mf] = *(const short8*)(Xs + off);
        }
    };

    short8 aa[2][4], bb[2][4];
    aload(0, aa[0]);
    load_b4(Wb, l, 0, bb[0]);

    // ---- 9 taps x 2 K-halves, depth-1 pipelined, no barriers
    #pragma unroll
    for (int s = 0; s < 18; ++s) {
        if (s < 17) {
            aload(s + 1, aa[(s + 1) & 1]);
            load_b4(Wb, l, s + 1, bb[(s + 1) & 1]);
        }
        #pragma unroll
        for (int mf = 0; mf < 4; ++mf) {
            #pragma unroll
            for (int of = 0; of < 4; ++of)
                acc[mf][of] = __builtin_amdgcn_mfma_f32_16x16x32_bf16(
                    aa[s & 1][mf], bb[s & 1][of], acc[mf][of], 0, 0, 0);
        }
    }

    if constexpr (STAGE == 1) {
        // ---- three par-scaled 1x1 experts on the center tap (regs only)
        float pvv[3][4];
        #pragma unroll
        for (int m = 0; m < 3; ++m)
            #pragma unroll
            for (int mf = 0; mf < 4; ++mf)
                pvv[m][mf] = par[((size_t)b * 3 + m) * HW_ +
                                 (gh0 + wv) * W_ + w0 + 16 * mf + ln15];
        aload(8, aa[0]);   // center tap, K-half 0 (reuse pipeline regs)
        aload(9, aa[1]);   // center tap, K-half 1
        #pragma unroll
        for (int m = 0; m < 3; ++m) {
            load_b4(Wb, l, 18 + 2 * m, bb[0]);
            load_b4(Wb, l, 19 + 2 * m, bb[1]);
            #pragma unroll
            for (int h = 0; h < 2; ++h) {
                #pragma unroll
                for (int mf = 0; mf < 4; ++mf) {
                    short8 sa;
                    #pragma unroll
                    for (int j = 0; j < 8; ++j)
                        sa[j] = (short)f2bf(bf2f((unsigned short)aa[h][mf][j]) * pvv[m][mf]);
                    #pragma unroll
                    for (int of = 0; of < 4; ++of)
                        acc[mf][of] = __builtin_amdgcn_mfma_f32_16x16x32_bf16(
                            sa, bb[h][of], acc[mf][of], 0, 0, 0);
                }
            }
        }

        // ---- epilogue: assemble full 128B lines in LDS, store dwordx4
        __shared__ unsigned short tl[4 * 64 * 64];   // 32 KB: [wv][px][o ^ swz]
        #pragma unroll
        for (int of = 0; of < 4; ++of) {
            int o = of * 16 + ln15;
            float bi = bias[b * 64 + o];
            #pragma unroll
            for (int mf = 0; mf < 4; ++mf) {
                #pragma unroll
                for (int q = 0; q < 4; ++q) {
                    int px = 16 * mf + 4 * g + q;
                    float v = fmaxf(acc[mf][of][q] + bi, 0.f);
                    tl[wv * 4096 + px * 64 + (o ^ ((px & 7) << 3))] = f2bf(v);
                }
            }
        }
        __syncthreads();
        #pragma unroll
        for (int it = 0; it < 8; ++it) {
            int tau = tid + it * 256;
            int row = tau >> 9;
            int px = (tau >> 3) & 63;
            int j = tau & 7;
            short8 v = *(const short8*)(tl + row * 4096 + px * 64 + ((j ^ (px & 7)) * 8));
            *(short8*)(Tp + ((size_t)b * PXP_ + (size_t)(gh0 + row + 1) * WP_ +
                             (w0 + 1 + px)) * 64 + j * 8) = v;
        }
    } else {
        // ---- epilogue: residual add + f32x4 out
        const int gh = gh0 + wv;
        #pragma unroll
        for (int of = 0; of < 4; ++of) {
            int o = of * 16 + ln15;
            float bi = bias[b * 64 + o];
            #pragma unroll
            for (int mf = 0; mf < 4; ++mf) {
                int gw = w0 + 16 * mf + g * 4;
                size_t idx = ((size_t)b * 64 + o) * HW_ + gh * W_ + gw;
                f32x4 xv = *(const f32x4*)(x_res + idx);
                f32x4 ov;
                #pragma unroll
                for (int q = 0; q < 4; ++q) ov[q] = xv[q] + acc[mf][of][q] + bi;
                *(f32x4*)(Fout + idx) = ov;
            }
        }
    }
}

extern "C" void kernel_launch(void* const* d_in, const int* in_sizes, int n_in,
                              void* d_out, int out_size, void* d_ws, size_t ws_size,
                              hipStream_t stream) {
    const float* x     = (const float*)d_in[0];
    const float* attn  = (const float*)d_in[1];
    const float* gamma = (const float*)d_in[2];
    const float* par   = (const float*)d_in[3];
    const float* w1    = (const float*)d_in[4];
    const float* b1    = (const float*)d_in[5];
    const float* w2    = (const float*)d_in[6];
    const float* b2    = (const float*)d_in[7];
    const float* w16   = (const float*)d_in[8];
    const float* w168  = (const float*)d_in[9];
    const float* w88   = (const float*)d_in[10];
    float* out = (float*)d_out;

    char* w = (char*)d_ws;
    unsigned short* W4_1 = (unsigned short*)w;                        // 786432 B
    unsigned short* W4_2 = (unsigned short*)(w + 786432);             // 589824 B
    float* bias1 = (float*)(w + 786432 + 589824);                     // 2048 B
    float* bias2 = (float*)(w + 786432 + 589824 + 2048);              // 2048 B
    unsigned short* X1p = (unsigned short*)(w + 1380352);             // 68161536 B
    unsigned short* Tp  = (unsigned short*)(w + 1380352 + 68161536);  // 68161536 B

    k_combine<<<dim3(2692), dim3(256), 0, stream>>>(attn, gamma, w1, b1, w2, b2,
                                                    w16, w168, w88, W4_1, W4_2, bias1, bias2);
    k_border<<<dim3(514), dim3(256), 0, stream>>>(X1p, Tp);
    k_prep<<<dim3(1024, 8), dim3(256), 0, stream>>>(x, X1p);

    dim3 grid(256, 8);
    k_conv<1><<<grid, dim3(256), 0, stream>>>(X1p, nullptr, par, W4_1, bias1, Tp, nullptr);
    k_conv<2><<<grid, dim3(256), 0, stream>>>(Tp, x, nullptr, W4_2, bias2, nullptr, out);
}

// Round 7
// 251.213 us; speedup vs baseline: 3.1204x; 1.4822x over previous
//
#include <hip/hip_runtime.h>
#include <hip/hip_bf16.h>

typedef __attribute__((ext_vector_type(8))) short short8;
typedef __attribute__((ext_vector_type(4))) float f32x4;

#define B_ 8
#define C_ 64
#define H_ 256
#define W_ 256
#define HW_ 65536
#define K_ 10
#define NS1 24
#define NS2 18
#define HP_ 258
#define WP_ 258
#define PXP_ (HP_*WP_)
#define SLABW 34

static __device__ __forceinline__ unsigned short f2bf(float f) {
    __hip_bfloat16 hb = __float2bfloat16(f);
    return *(unsigned short*)&hb;
}
static __device__ __forceinline__ float bf2f(unsigned short u) {
    unsigned v = ((unsigned)u) << 16;
    float f;
    __builtin_memcpy(&f, &v, 4);
    return f;
}

// async global->LDS 16B (dest = wave-uniform base + lane*16, linear in tau)
static __device__ __forceinline__ void gload_lds16(const void* g, void* l) {
    __builtin_amdgcn_global_load_lds(
        (const __attribute__((address_space(1))) unsigned int*)(unsigned long long)g,
        (__attribute__((address_space(3))) unsigned int*)(unsigned int)(unsigned long long)l,
        16, 0, 0);
}

// ---------------------------------------------------------------------------
// Fragment-ordered, gamma-folded, expert-mixed weights + biases.
// W4_1: [b][24 steps][4 of][64 lane][8] bf16 (0..17 conv taps, 18..23 1x1)
// W4_2: [b][18 steps][4][64][8] bf16
// ---------------------------------------------------------------------------
__global__ void k_combine(const float* __restrict__ attn, const float* __restrict__ gamma,
                          const float* __restrict__ w1, const float* __restrict__ b1,
                          const float* __restrict__ w2, const float* __restrict__ b2,
                          const float* __restrict__ w16, const float* __restrict__ w168,
                          const float* __restrict__ w88,
                          unsigned short* __restrict__ W4_1, unsigned short* __restrict__ W4_2,
                          float* __restrict__ bias1, float* __restrict__ bias2) {
    const int N1 = B_ * NS1 * 2048;
    const int N2 = B_ * NS2 * 2048;
    int gid = blockIdx.x * 256 + threadIdx.x;
    if (gid < N1) {
        int b = gid / (NS1 * 2048);
        int r = gid - b * (NS1 * 2048);
        int s = r >> 11;
        int r2 = r & 2047;
        int of = r2 >> 9, l = (r2 >> 3) & 63, j = r2 & 7;
        int o = of * 16 + (l & 15);
        int g = l >> 4;
        float val;
        if (s < 18) {
            int t = s >> 1, h = s & 1;
            int c = h * 32 + g * 8 + j;
            float acc = 0.f;
            #pragma unroll
            for (int k = 0; k < K_; ++k)
                acc += attn[b * K_ + k] * w2[((size_t)(k * 64 + o) * 64 + c) * 9 + t];
            val = acc * gamma[b * 64 + o];
        } else {
            int e = s - 18;
            int m = e >> 1, h = e & 1;
            int c = h * 32 + g * 8 + j;
            const float* wm = (m == 0) ? w16 : (m == 1 ? w168 : w88);
            val = wm[o * 64 + c];
        }
        W4_1[gid] = f2bf(val);
    } else if (gid < N1 + N2) {
        int gid2 = gid - N1;
        int b = gid2 / (NS2 * 2048);
        int r = gid2 - b * (NS2 * 2048);
        int s = r >> 11;
        int r2 = r & 2047;
        int of = r2 >> 9, l = (r2 >> 3) & 63, j = r2 & 7;
        int o = of * 16 + (l & 15);
        int g = l >> 4;
        int t = s >> 1, h = s & 1;
        int c = h * 32 + g * 8 + j;
        float acc = 0.f;
        #pragma unroll
        for (int k = 0; k < K_; ++k)
            acc += attn[b * K_ + k] * w1[((size_t)(k * 64 + o) * 64 + c) * 9 + t];
        W4_2[gid2] = f2bf(acc * gamma[b * 64 + o]);
    } else if (gid < N1 + N2 + 1024) {
        int id2 = gid - N1 - N2;
        int b = id2 >> 7;
        int rest = id2 & 127;
        int o = rest >> 1;
        int which = rest & 1;
        const float* bb = which ? b1 : b2;
        float acc = 0.f;
        #pragma unroll
        for (int k = 0; k < K_; ++k) acc += attn[b * K_ + k] * bb[k * 64 + o];
        float v = acc * gamma[b * 64 + o];
        if (which) bias2[b * 64 + o] = v; else bias1[b * 64 + o] = v;
    }
}

// ---------------------------------------------------------------------------
// Zero halo borders of the padded X1p / Tp buffers.
// ---------------------------------------------------------------------------
__global__ void k_border(unsigned short* __restrict__ X1p, unsigned short* __restrict__ Tp) {
    int gid = blockIdx.x * 256 + threadIdx.x;
    if (gid >= 2 * B_ * 1028 * 8) return;
    int chunk = gid & 7;
    int rest = gid >> 3;
    int p = rest % 1028;
    int rb = rest / 1028;
    int buf = rb & 1, b = rb >> 1;
    int row, col;
    if (p < 258) { row = 0; col = p; }
    else if (p < 516) { row = 257; col = p - 258; }
    else if (p < 772) { row = p - 516 + 1; col = 0; }
    else { row = p - 772 + 1; col = 257; }
    unsigned short* base = (buf ? Tp : X1p) +
        ((size_t)b * PXP_ + (size_t)row * WP_ + col) * 64 + chunk * 8;
    *(short8*)base = (short8){0, 0, 0, 0, 0, 0, 0, 0};
}

// ---------------------------------------------------------------------------
// x [b][64][HW] f32  ->  X1p [b][258][258][64] bf16 (interior only)
// ---------------------------------------------------------------------------
__global__ __launch_bounds__(256) void k_prep(const float* __restrict__ x,
                                              unsigned short* __restrict__ X1p) {
    __shared__ float ls[64][65];
    const int b = blockIdx.y;
    const int px0 = blockIdx.x * 64;
    const int row = px0 >> 8;
    const int col0 = px0 & 255;
    const int t = threadIdx.x;
    for (int e = t; e < 4096; e += 256) {
        int ch = e >> 6, px = e & 63;
        ls[ch][px] = x[((size_t)b * 64 + ch) * HW_ + px0 + px];
    }
    __syncthreads();
    unsigned short* dst = X1p + ((size_t)b * PXP_ + (size_t)(row + 1) * WP_ + col0 + 1) * 64;
    for (int e = t; e < 4096; e += 256) {
        int ch = e & 63, px = e >> 6;
        dst[(size_t)px * 64 + ch] = f2bf(ls[ch][px]);
    }
}

// ---- B frags: fragment-ordered global, 1KB coalesced per of
static __device__ __forceinline__ void load_b4(const unsigned short* __restrict__ Wb,
                                               int l, int s, short8* d) {
    const unsigned short* wp = Wb + s * 2048 + l * 8;
    d[0] = *(const short8*)(wp);
    d[1] = *(const short8*)(wp + 512);
    d[2] = *(const short8*)(wp + 1024);
    d[3] = *(const short8*)(wp + 1536);
}

// ---------------------------------------------------------------------------
// Implicit-GEMM conv3x3 via MFMA. Tile: 4 img-rows x 32 w x 64 o, 4 waves.
// Slab [6][34][64] bf16 (26.1 KB) staged via async global_load_lds from the
// padded input; conv1 output lines assembled in slab-aliased LDS.
// ---------------------------------------------------------------------------
template<int STAGE>
__global__ __launch_bounds__(256, 4) void k_conv(
    const unsigned short* __restrict__ Xp,    // [b][258][258][64] bf16 padded
    const float* __restrict__ x_res,          // stage2 residual [b][o][px]
    const float* __restrict__ par,            // stage1 [b][3][HW]
    const unsigned short* __restrict__ W4,    // [b][NS][4][64][8] bf16
    const float* __restrict__ bias,           // [b][64]
    unsigned short* __restrict__ Tp,          // stage1 out [b][258][258][64] bf16
    float* __restrict__ Fout)                 // stage2 out [b][64][HW] f32
{
    __shared__ short xs[6 * SLABW * 64];      // 26112 B (aliased as tl in epilogue)

    const int tid = threadIdx.x;
    const int l = tid & 63;
    const int wv = tid >> 6;
    const int b = blockIdx.y;
    const int rblk = blockIdx.x >> 3;         // 0..63
    const int cblk = blockIdx.x & 7;          // 0..7
    const int gh0 = rblk * 4, w0 = cblk * 32;
    const int ln15 = l & 15, g = l >> 4;

    const char* XbP = (const char*)Xp + (size_t)b * PXP_ * 128;
    const unsigned short* Wb = W4 + (size_t)b * ((STAGE == 1 ? NS1 : NS2) * 2048);

    f32x4 acc[2][4];
    #pragma unroll
    for (int mf = 0; mf < 2; ++mf)
        #pragma unroll
        for (int of = 0; of < 4; ++of)
            acc[mf][of] = (f32x4){0.f, 0.f, 0.f, 0.f};

    // ---- async-stage slab [6 rows][34 px][8 chunks]; swizzled source, linear dest
    #pragma unroll
    for (int it = 0; it < 7; ++it) {
        int tau = tid + it * 256;
        if (tau < 6 * SLABW * 8) {
            int slot = tau & 7;
            int rest = tau >> 3;
            int px = rest % SLABW;
            int row = rest / SLABW;
            int cb = slot ^ (px & 7);
            const char* src = XbP + ((size_t)(gh0 + row) * WP_ + (w0 + px)) * 128 + cb * 16;
            gload_lds16(src, (char*)xs + (size_t)tau * 16);
        }
    }

    // A-frag loader (all call sites have compile-time s)
    auto aload = [&](int s, short8* d) {
        const int t = s >> 1, h = s & 1;
        const int dh = t / 3, dw = t - 3 * dh;
        #pragma unroll
        for (int mf = 0; mf < 2; ++mf) {
            int idx = 16 * mf + ln15 + dw;
            d[mf] = *(const short8*)((const char*)xs + ((wv + dh) * SLABW + idx) * 128 +
                                     ((((h << 2) | g) ^ (idx & 7)) << 4));
        }
    };

    short8 aa[2][2], bb[2][4];
    load_b4(Wb, l, 0, bb[0]);      // overlap with the LDS drain
    asm volatile("s_waitcnt vmcnt(0)" ::: "memory");
    __syncthreads();
    aload(0, aa[0]);

    // ---- 9 taps x 2 K-halves, depth-1 pipelined
    #pragma unroll
    for (int s = 0; s < 18; ++s) {
        if (s < 17) {
            aload(s + 1, aa[(s + 1) & 1]);
            load_b4(Wb, l, s + 1, bb[(s + 1) & 1]);
        }
        #pragma unroll
        for (int mf = 0; mf < 2; ++mf) {
            #pragma unroll
            for (int of = 0; of < 4; ++of)
                acc[mf][of] = __builtin_amdgcn_mfma_f32_16x16x32_bf16(
                    aa[s & 1][mf], bb[s & 1][of], acc[mf][of], 0, 0, 0);
        }
    }

    if constexpr (STAGE == 1) {
        // ---- three par-scaled 1x1 experts on the center tap (regs only)
        float pvv[3][2];
        #pragma unroll
        for (int m = 0; m < 3; ++m)
            #pragma unroll
            for (int mf = 0; mf < 2; ++mf)
                pvv[m][mf] = par[((size_t)b * 3 + m) * HW_ +
                                 (gh0 + wv) * W_ + w0 + 16 * mf + ln15];
        aload(8, aa[0]);   // center tap, K-half 0
        aload(9, aa[1]);   // center tap, K-half 1
        #pragma unroll
        for (int m = 0; m < 3; ++m) {
            load_b4(Wb, l, 18 + 2 * m, bb[0]);
            load_b4(Wb, l, 19 + 2 * m, bb[1]);
            #pragma unroll
            for (int h = 0; h < 2; ++h) {
                #pragma unroll
                for (int mf = 0; mf < 2; ++mf) {
                    short8 sa;
                    #pragma unroll
                    for (int j = 0; j < 8; ++j)
                        sa[j] = (short)f2bf(bf2f((unsigned short)aa[h][mf][j]) * pvv[m][mf]);
                    #pragma unroll
                    for (int of = 0; of < 4; ++of)
                        acc[mf][of] = __builtin_amdgcn_mfma_f32_16x16x32_bf16(
                            sa, bb[h][of], acc[mf][of], 0, 0, 0);
                }
            }
        }

        // ---- epilogue: assemble 128B lines in slab-aliased LDS, store dwordx4
        __syncthreads();                       // all slab reads done
        unsigned short* tl = (unsigned short*)xs;   // [wv][32 px][64 o^swz] = 16 KB
        #pragma unroll
        for (int of = 0; of < 4; ++of) {
            int o = of * 16 + ln15;
            float bi = bias[b * 64 + o];
            #pragma unroll
            for (int mf = 0; mf < 2; ++mf) {
                #pragma unroll
                for (int q = 0; q < 4; ++q) {
                    int px = 16 * mf + 4 * g + q;
                    float v = fmaxf(acc[mf][of][q] + bi, 0.f);
                    tl[wv * 2048 + px * 64 + (o ^ ((px & 7) << 3))] = f2bf(v);
                }
            }
        }
        __syncthreads();
        #pragma unroll
        for (int it = 0; it < 4; ++it) {
            int tau = tid + it * 256;
            int row = tau >> 8;
            int px = (tau >> 3) & 31;
            int j = tau & 7;
            short8 v = *(const short8*)(tl + row * 2048 + px * 64 + ((j ^ (px & 7)) * 8));
            *(short8*)(Tp + ((size_t)b * PXP_ + (size_t)(gh0 + row + 1) * WP_ +
                             (w0 + 1 + px)) * 64 + j * 8) = v;
        }
    } else {
        // ---- epilogue: residual add + f32x4 out
        const int gh = gh0 + wv;
        #pragma unroll
        for (int of = 0; of < 4; ++of) {
            int o = of * 16 + ln15;
            float bi = bias[b * 64 + o];
            #pragma unroll
            for (int mf = 0; mf < 2; ++mf) {
                int gw = w0 + 16 * mf + g * 4;
                size_t idx = ((size_t)b * 64 + o) * HW_ + gh * W_ + gw;
                f32x4 xv = *(const f32x4*)(x_res + idx);
                f32x4 ov;
                #pragma unroll
                for (int q = 0; q < 4; ++q) ov[q] = xv[q] + acc[mf][of][q] + bi;
                *(f32x4*)(Fout + idx) = ov;
            }
        }
    }
}

extern "C" void kernel_launch(void* const* d_in, const int* in_sizes, int n_in,
                              void* d_out, int out_size, void* d_ws, size_t ws_size,
                              hipStream_t stream) {
    const float* x     = (const float*)d_in[0];
    const float* attn  = (const float*)d_in[1];
    const float* gamma = (const float*)d_in[2];
    const float* par   = (const float*)d_in[3];
    const float* w1    = (const float*)d_in[4];
    const float* b1    = (const float*)d_in[5];
    const float* w2    = (const float*)d_in[6];
    const float* b2    = (const float*)d_in[7];
    const float* w16   = (const float*)d_in[8];
    const float* w168  = (const float*)d_in[9];
    const float* w88   = (const float*)d_in[10];
    float* out = (float*)d_out;

    char* w = (char*)d_ws;
    unsigned short* W4_1 = (unsigned short*)w;                        // 786432 B
    unsigned short* W4_2 = (unsigned short*)(w + 786432);             // 589824 B
    float* bias1 = (float*)(w + 786432 + 589824);                     // 2048 B
    float* bias2 = (float*)(w + 786432 + 589824 + 2048);              // 2048 B
    unsigned short* X1p = (unsigned short*)(w + 1380352);             // 68161536 B
    unsigned short* Tp  = (unsigned short*)(w + 1380352 + 68161536);  // 68161536 B

    k_combine<<<dim3(2692), dim3(256), 0, stream>>>(attn, gamma, w1, b1, w2, b2,
                                                    w16, w168, w88, W4_1, W4_2, bias1, bias2);
    k_border<<<dim3(514), dim3(256), 0, stream>>>(X1p, Tp);
    k_prep<<<dim3(1024, 8), dim3(256), 0, stream>>>(x, X1p);

    dim3 grid(512, 8);
    k_conv<1><<<grid, dim3(256), 0, stream>>>(X1p, nullptr, par, W4_1, bias1, Tp, nullptr);
    k_conv<2><<<grid, dim3(256), 0, stream>>>(Tp, x, nullptr, W4_2, bias2, nullptr, out);
}

// Round 8
// 199.782 us; speedup vs baseline: 3.9237x; 1.2574x over previous
//
#include <hip/hip_runtime.h>
#include <hip/hip_bf16.h>

typedef __attribute__((ext_vector_type(8))) short short8;
typedef __attribute__((ext_vector_type(4))) float f32x4;

#define B_ 8
#define C_ 64
#define H_ 256
#define W_ 256
#define HW_ 65536
#define K_ 10
#define NS1 24
#define NS2 18
#define HP_ 258
#define WP_ 258
#define PXP_ (HP_*WP_)
#define SLABW 34

static __device__ __forceinline__ unsigned short f2bf(float f) {
    __hip_bfloat16 hb = __float2bfloat16(f);
    return *(unsigned short*)&hb;
}
static __device__ __forceinline__ float bf2f(unsigned short u) {
    unsigned v = ((unsigned)u) << 16;
    float f;
    __builtin_memcpy(&f, &v, 4);
    return f;
}

// async global->LDS 16B (dest = wave-uniform base + lane*16, linear in tau)
static __device__ __forceinline__ void gload_lds16(const void* g, void* l) {
    __builtin_amdgcn_global_load_lds(
        (const __attribute__((address_space(1))) unsigned int*)(unsigned long long)g,
        (__attribute__((address_space(3))) unsigned int*)(unsigned int)(unsigned long long)l,
        16, 0, 0);
}

// ---------------------------------------------------------------------------
// Fragment-ordered, gamma-folded, expert-mixed weights + biases.
// W4_1: [b][24 steps][4 of][64 lane][8] bf16 (0..17 conv taps, 18..23 1x1)
// W4_2: [b][18 steps][4][64][8] bf16
// ---------------------------------------------------------------------------
__global__ void k_combine(const float* __restrict__ attn, const float* __restrict__ gamma,
                          const float* __restrict__ w1, const float* __restrict__ b1,
                          const float* __restrict__ w2, const float* __restrict__ b2,
                          const float* __restrict__ w16, const float* __restrict__ w168,
                          const float* __restrict__ w88,
                          unsigned short* __restrict__ W4_1, unsigned short* __restrict__ W4_2,
                          float* __restrict__ bias1, float* __restrict__ bias2) {
    const int N1 = B_ * NS1 * 2048;
    const int N2 = B_ * NS2 * 2048;
    int gid = blockIdx.x * 256 + threadIdx.x;
    if (gid < N1) {
        int b = gid / (NS1 * 2048);
        int r = gid - b * (NS1 * 2048);
        int s = r >> 11;
        int r2 = r & 2047;
        int of = r2 >> 9, l = (r2 >> 3) & 63, j = r2 & 7;
        int o = of * 16 + (l & 15);
        int g = l >> 4;
        float val;
        if (s < 18) {
            int t = s >> 1, h = s & 1;
            int c = h * 32 + g * 8 + j;
            float acc = 0.f;
            #pragma unroll
            for (int k = 0; k < K_; ++k)
                acc += attn[b * K_ + k] * w2[((size_t)(k * 64 + o) * 64 + c) * 9 + t];
            val = acc * gamma[b * 64 + o];
        } else {
            int e = s - 18;
            int m = e >> 1, h = e & 1;
            int c = h * 32 + g * 8 + j;
            const float* wm = (m == 0) ? w16 : (m == 1 ? w168 : w88);
            val = wm[o * 64 + c];
        }
        W4_1[gid] = f2bf(val);
    } else if (gid < N1 + N2) {
        int gid2 = gid - N1;
        int b = gid2 / (NS2 * 2048);
        int r = gid2 - b * (NS2 * 2048);
        int s = r >> 11;
        int r2 = r & 2047;
        int of = r2 >> 9, l = (r2 >> 3) & 63, j = r2 & 7;
        int o = of * 16 + (l & 15);
        int g = l >> 4;
        int t = s >> 1, h = s & 1;
        int c = h * 32 + g * 8 + j;
        float acc = 0.f;
        #pragma unroll
        for (int k = 0; k < K_; ++k)
            acc += attn[b * K_ + k] * w1[((size_t)(k * 64 + o) * 64 + c) * 9 + t];
        W4_2[gid2] = f2bf(acc * gamma[b * 64 + o]);
    } else if (gid < N1 + N2 + 1024) {
        int id2 = gid - N1 - N2;
        int b = id2 >> 7;
        int rest = id2 & 127;
        int o = rest >> 1;
        int which = rest & 1;
        const float* bb = which ? b1 : b2;
        float acc = 0.f;
        #pragma unroll
        for (int k = 0; k < K_; ++k) acc += attn[b * K_ + k] * bb[k * 64 + o];
        float v = acc * gamma[b * 64 + o];
        if (which) bias2[b * 64 + o] = v; else bias1[b * 64 + o] = v;
    }
}

// ---------------------------------------------------------------------------
// Zero halo borders of the padded X1p / Tp buffers.
// ---------------------------------------------------------------------------
__global__ void k_border(unsigned short* __restrict__ X1p, unsigned short* __restrict__ Tp) {
    int gid = blockIdx.x * 256 + threadIdx.x;
    if (gid >= 2 * B_ * 1028 * 8) return;
    int chunk = gid & 7;
    int rest = gid >> 3;
    int p = rest % 1028;
    int rb = rest / 1028;
    int buf = rb & 1, b = rb >> 1;
    int row, col;
    if (p < 258) { row = 0; col = p; }
    else if (p < 516) { row = 257; col = p - 258; }
    else if (p < 772) { row = p - 516 + 1; col = 0; }
    else { row = p - 772 + 1; col = 257; }
    unsigned short* base = (buf ? Tp : X1p) +
        ((size_t)b * PXP_ + (size_t)row * WP_ + col) * 64 + chunk * 8;
    *(short8*)base = (short8){0, 0, 0, 0, 0, 0, 0, 0};
}

// ---------------------------------------------------------------------------
// x [b][64][HW] f32  ->  X1p [b][258][258][64] bf16 (interior only)
// ---------------------------------------------------------------------------
__global__ __launch_bounds__(256) void k_prep(const float* __restrict__ x,
                                              unsigned short* __restrict__ X1p) {
    __shared__ float ls[64][65];
    const int b = blockIdx.y;
    const int px0 = blockIdx.x * 64;
    const int row = px0 >> 8;
    const int col0 = px0 & 255;
    const int t = threadIdx.x;
    for (int e = t; e < 4096; e += 256) {
        int ch = e >> 6, px = e & 63;
        ls[ch][px] = x[((size_t)b * 64 + ch) * HW_ + px0 + px];
    }
    __syncthreads();
    unsigned short* dst = X1p + ((size_t)b * PXP_ + (size_t)(row + 1) * WP_ + col0 + 1) * 64;
    for (int e = t; e < 4096; e += 256) {
        int ch = e & 63, px = e >> 6;
        dst[(size_t)px * 64 + ch] = f2bf(ls[ch][px]);
    }
}

// ---------------------------------------------------------------------------
// Implicit-GEMM conv3x3 via MFMA. Tile: 4 img-rows x 32 w x 64 o, 4 waves.
// A: slab [6][34][64] bf16 (26.1 KB) via async global_load_lds (XOR-swizzled
// source, linear dest). B: 3-slot x 4KB LDS ring, counted-vmcnt pipeline
// (prefetch distance 2, s_waitcnt vmcnt(1), raw s_barrier - never drain-0).
// ---------------------------------------------------------------------------
template<int STAGE>
__global__ __launch_bounds__(256, 4) void k_conv(
    const unsigned short* __restrict__ Xp,    // [b][258][258][64] bf16 padded
    const float* __restrict__ x_res,          // stage2 residual [b][o][px]
    const float* __restrict__ par,            // stage1 [b][3][HW]
    const unsigned short* __restrict__ W4,    // [b][NS][4][64][8] bf16
    const float* __restrict__ bias,           // [b][64]
    unsigned short* __restrict__ Tp,          // stage1 out [b][258][258][64] bf16
    float* __restrict__ Fout)                 // stage2 out [b][64][HW] f32
{
    constexpr int NS = (STAGE == 1) ? NS1 : NS2;
    __shared__ short xs[6 * SLABW * 64];      // 26112 B (aliased as tl in epilogue)
    __shared__ short bring[3 * 2048];         // 12288 B B-ring (3 slots x 4KB)

    const int tid = threadIdx.x;
    const int l = tid & 63;
    const int wv = tid >> 6;
    const int b = blockIdx.y;
    // XCD-aware bijective swizzle (512 blocks = 8 XCD x 64)
    const int bswz = (blockIdx.x & 7) * 64 + (blockIdx.x >> 3);
    const int rblk = bswz >> 3;               // 0..63
    const int cblk = bswz & 7;                // 0..7
    const int gh0 = rblk * 4, w0 = cblk * 32;
    const int ln15 = l & 15, g = l >> 4;

    const char* XbP = (const char*)Xp + (size_t)b * PXP_ * 128;
    const unsigned short* Wb = W4 + (size_t)b * (NS * 2048);

    // per-lane par row values (stage1) - loaded before async stages (oldest in queue)
    float pvv[3][2];
    if constexpr (STAGE == 1) {
        #pragma unroll
        for (int m = 0; m < 3; ++m)
            #pragma unroll
            for (int mf = 0; mf < 2; ++mf)
                pvv[m][mf] = par[((size_t)b * 3 + m) * HW_ +
                                 (gh0 + wv) * W_ + w0 + 16 * mf + ln15];
    }

    f32x4 acc[2][4];
    #pragma unroll
    for (int mf = 0; mf < 2; ++mf)
        #pragma unroll
        for (int of = 0; of < 4; ++of)
            acc[mf][of] = (f32x4){0.f, 0.f, 0.f, 0.f};

    // ---- async-stage slab [6 rows][34 px][8 chunks]; swizzled source, linear dest
    #pragma unroll
    for (int it = 0; it < 7; ++it) {
        int tau = tid + it * 256;
        if (tau < 6 * SLABW * 8) {
            int slot = tau & 7;
            int rest = tau >> 3;
            int px = rest % SLABW;
            int row = rest / SLABW;
            int cb = slot ^ (px & 7);
            gload_lds16(XbP + ((size_t)(gh0 + row) * WP_ + (w0 + px)) * 128 + cb * 16,
                        (char*)xs + (size_t)tau * 16);
        }
    }
    // ---- B stage: 4KB/step, linear copy (W4 already fragment-ordered)
    auto stage_b = [&](int s) {
        gload_lds16((const char*)Wb + (size_t)s * 4096 + tid * 16,
                    (char*)bring + (s % 3) * 4096 + tid * 16);
    };
    stage_b(0);
    stage_b(1);

    // A-frag loader (all call sites have compile-time s)
    auto aload = [&](int s, short8* d) {
        const int t = s >> 1, h = s & 1;
        const int dh = t / 3, dw = t - 3 * dh;
        #pragma unroll
        for (int mf = 0; mf < 2; ++mf) {
            int idx = 16 * mf + ln15 + dw;
            d[mf] = *(const short8*)((const char*)xs + ((wv + dh) * SLABW + idx) * 128 +
                                     ((((h << 2) | g) ^ (idx & 7)) << 4));
        }
    };

    // slab + B0 landed (B1 may stay in flight); raw barrier (no drain-0)
    asm volatile("s_waitcnt vmcnt(1)" ::: "memory");
    __builtin_amdgcn_s_barrier();

    short8 aa[2][2];
    aload(0, aa[0]);

    #pragma unroll
    for (int s = 0; s < NS; ++s) {
        // B-frags from ring slot s%3 (contiguous 1KB per of -> conflict-free)
        const char* rbase = (const char*)bring + (s % 3) * 4096 + (size_t)l * 16;
        short8 bf0 = *(const short8*)(rbase);
        short8 bf1 = *(const short8*)(rbase + 1024);
        short8 bf2 = *(const short8*)(rbase + 2048);
        short8 bf3 = *(const short8*)(rbase + 3072);
        if (s + 2 < NS) stage_b(s + 2);     // slot (s+2)%3 = (s-1)%3, free since last barrier
        if (s + 1 < NS) {                   // A prefetch for next step (static slab)
            if (STAGE == 2 || s + 1 < 18) aload(s + 1, aa[(s + 1) & 1]);
            else aload(8 + ((s + 1) & 1), aa[(s + 1) & 1]);  // par steps: center tap
        }
        short8 af[2];
        if (STAGE == 1 && s >= 18) {        // par-scaled 1x1 expert steps
            const int m = (s - 18) >> 1;
            #pragma unroll
            for (int mf = 0; mf < 2; ++mf)
                #pragma unroll
                for (int j = 0; j < 8; ++j)
                    af[mf][j] = (short)f2bf(bf2f((unsigned short)aa[s & 1][mf][j]) * pvv[m][mf]);
        } else {
            af[0] = aa[s & 1][0];
            af[1] = aa[s & 1][1];
        }
        #pragma unroll
        for (int mf = 0; mf < 2; ++mf) {
            acc[mf][0] = __builtin_amdgcn_mfma_f32_16x16x32_bf16(af[mf], bf0, acc[mf][0], 0, 0, 0);
            acc[mf][1] = __builtin_amdgcn_mfma_f32_16x16x32_bf16(af[mf], bf1, acc[mf][1], 0, 0, 0);
            acc[mf][2] = __builtin_amdgcn_mfma_f32_16x16x32_bf16(af[mf], bf2, acc[mf][2], 0, 0, 0);
            acc[mf][3] = __builtin_amdgcn_mfma_f32_16x16x32_bf16(af[mf], bf3, acc[mf][3], 0, 0, 0);
        }
        if (s + 1 < NS) {
            // B(s+1) landed; keep B(s+2) in flight (counted, never 0 mid-loop)
            if (s + 3 <= NS) asm volatile("s_waitcnt vmcnt(1)" ::: "memory");
            else             asm volatile("s_waitcnt vmcnt(0)" ::: "memory");
            __builtin_amdgcn_s_barrier();
        }
    }

    if constexpr (STAGE == 1) {
        // ---- epilogue: assemble 128B lines in slab-aliased LDS, store dwordx4
        __syncthreads();                       // all slab/ring reads done
        unsigned short* tl = (unsigned short*)xs;   // [wv][32 px][64 o^swz] = 16 KB
        #pragma unroll
        for (int of = 0; of < 4; ++of) {
            int o = of * 16 + ln15;
            float bi = bias[b * 64 + o];
            #pragma unroll
            for (int mf = 0; mf < 2; ++mf) {
                #pragma unroll
                for (int q = 0; q < 4; ++q) {
                    int px = 16 * mf + 4 * g + q;
                    float v = fmaxf(acc[mf][of][q] + bi, 0.f);
                    tl[wv * 2048 + px * 64 + (o ^ ((px & 7) << 3))] = f2bf(v);
                }
            }
        }
        __syncthreads();
        #pragma unroll
        for (int it = 0; it < 4; ++it) {
            int tau = tid + it * 256;
            int row = tau >> 8;
            int px = (tau >> 3) & 31;
            int j = tau & 7;
            short8 v = *(const short8*)(tl + row * 2048 + px * 64 + ((j ^ (px & 7)) * 8));
            *(short8*)(Tp + ((size_t)b * PXP_ + (size_t)(gh0 + row + 1) * WP_ +
                             (w0 + 1 + px)) * 64 + j * 8) = v;
        }
    } else {
        // ---- epilogue: residual add + f32x4 out
        const int gh = gh0 + wv;
        #pragma unroll
        for (int of = 0; of < 4; ++of) {
            int o = of * 16 + ln15;
            float bi = bias[b * 64 + o];
            #pragma unroll
            for (int mf = 0; mf < 2; ++mf) {
                int gw = w0 + 16 * mf + g * 4;
                size_t idx = ((size_t)b * 64 + o) * HW_ + gh * W_ + gw;
                f32x4 xv = *(const f32x4*)(x_res + idx);
                f32x4 ov;
                #pragma unroll
                for (int q = 0; q < 4; ++q) ov[q] = xv[q] + acc[mf][of][q] + bi;
                *(f32x4*)(Fout + idx) = ov;
            }
        }
    }
}

extern "C" void kernel_launch(void* const* d_in, const int* in_sizes, int n_in,
                              void* d_out, int out_size, void* d_ws, size_t ws_size,
                              hipStream_t stream) {
    const float* x     = (const float*)d_in[0];
    const float* attn  = (const float*)d_in[1];
    const float* gamma = (const float*)d_in[2];
    const float* par   = (const float*)d_in[3];
    const float* w1    = (const float*)d_in[4];
    const float* b1    = (const float*)d_in[5];
    const float* w2    = (const float*)d_in[6];
    const float* b2    = (const float*)d_in[7];
    const float* w16   = (const float*)d_in[8];
    const float* w168  = (const float*)d_in[9];
    const float* w88   = (const float*)d_in[10];
    float* out = (float*)d_out;

    char* w = (char*)d_ws;
    unsigned short* W4_1 = (unsigned short*)w;                        // 786432 B
    unsigned short* W4_2 = (unsigned short*)(w + 786432);             // 589824 B
    float* bias1 = (float*)(w + 786432 + 589824);                     // 2048 B
    float* bias2 = (float*)(w + 786432 + 589824 + 2048);              // 2048 B
    unsigned short* X1p = (unsigned short*)(w + 1380352);             // 68161536 B
    unsigned short* Tp  = (unsigned short*)(w + 1380352 + 68161536);  // 68161536 B

    k_combine<<<dim3(2692), dim3(256), 0, stream>>>(attn, gamma, w1, b1, w2, b2,
                                                    w16, w168, w88, W4_1, W4_2, bias1, bias2);
    k_border<<<dim3(514), dim3(256), 0, stream>>>(X1p, Tp);
    k_prep<<<dim3(1024, 8), dim3(256), 0, stream>>>(x, X1p);

    dim3 grid(512, 8);
    k_conv<1><<<grid, dim3(256), 0, stream>>>(X1p, nullptr, par, W4_1, bias1, Tp, nullptr);
    k_conv<2><<<grid, dim3(256), 0, stream>>>(Tp, x, nullptr, W4_2, bias2, nullptr, out);
}

// Round 9
// 197.723 us; speedup vs baseline: 3.9646x; 1.0104x over previous
//
#include <hip/hip_runtime.h>
#include <hip/hip_bf16.h>

typedef __attribute__((ext_vector_type(8))) short short8;
typedef __attribute__((ext_vector_type(4))) float f32x4;

#define B_ 8
#define C_ 64
#define H_ 256
#define W_ 256
#define HW_ 65536
#define K_ 10
#define NS1 24
#define NS2 18
#define HP_ 258
#define WP_ 258
#define PXP_ (HP_*WP_)
#define SLABW 34
#define SLABR 10

static __device__ __forceinline__ unsigned short f2bf(float f) {
    __hip_bfloat16 hb = __float2bfloat16(f);
    return *(unsigned short*)&hb;
}
static __device__ __forceinline__ float bf2f(unsigned short u) {
    unsigned v = ((unsigned)u) << 16;
    float f;
    __builtin_memcpy(&f, &v, 4);
    return f;
}

// async global->LDS 16B (dest = wave-uniform base + lane*16, linear in tau)
static __device__ __forceinline__ void gload_lds16(const void* g, void* l) {
    __builtin_amdgcn_global_load_lds(
        (const __attribute__((address_space(1))) unsigned int*)(unsigned long long)g,
        (__attribute__((address_space(3))) unsigned int*)(unsigned int)(unsigned long long)l,
        16, 0, 0);
}

// ---------------------------------------------------------------------------
// Fragment-ordered, gamma-folded, expert-mixed weights + biases.
// W4_1: [b][24 steps][4 of][64 lane][8] bf16 (0..17 conv taps, 18..23 1x1)
// W4_2: [b][18 steps][4][64][8] bf16
// ---------------------------------------------------------------------------
__global__ void k_combine(const float* __restrict__ attn, const float* __restrict__ gamma,
                          const float* __restrict__ w1, const float* __restrict__ b1,
                          const float* __restrict__ w2, const float* __restrict__ b2,
                          const float* __restrict__ w16, const float* __restrict__ w168,
                          const float* __restrict__ w88,
                          unsigned short* __restrict__ W4_1, unsigned short* __restrict__ W4_2,
                          float* __restrict__ bias1, float* __restrict__ bias2) {
    const int N1 = B_ * NS1 * 2048;
    const int N2 = B_ * NS2 * 2048;
    int gid = blockIdx.x * 256 + threadIdx.x;
    if (gid < N1) {
        int b = gid / (NS1 * 2048);
        int r = gid - b * (NS1 * 2048);
        int s = r >> 11;
        int r2 = r & 2047;
        int of = r2 >> 9, l = (r2 >> 3) & 63, j = r2 & 7;
        int o = of * 16 + (l & 15);
        int g = l >> 4;
        float val;
        if (s < 18) {
            int t = s >> 1, h = s & 1;
            int c = h * 32 + g * 8 + j;
            float acc = 0.f;
            #pragma unroll
            for (int k = 0; k < K_; ++k)
                acc += attn[b * K_ + k] * w2[((size_t)(k * 64 + o) * 64 + c) * 9 + t];
            val = acc * gamma[b * 64 + o];
        } else {
            int e = s - 18;
            int m = e >> 1, h = e & 1;
            int c = h * 32 + g * 8 + j;
            const float* wm = (m == 0) ? w16 : (m == 1 ? w168 : w88);
            val = wm[o * 64 + c];
        }
        W4_1[gid] = f2bf(val);
    } else if (gid < N1 + N2) {
        int gid2 = gid - N1;
        int b = gid2 / (NS2 * 2048);
        int r = gid2 - b * (NS2 * 2048);
        int s = r >> 11;
        int r2 = r & 2047;
        int of = r2 >> 9, l = (r2 >> 3) & 63, j = r2 & 7;
        int o = of * 16 + (l & 15);
        int g = l >> 4;
        int t = s >> 1, h = s & 1;
        int c = h * 32 + g * 8 + j;
        float acc = 0.f;
        #pragma unroll
        for (int k = 0; k < K_; ++k)
            acc += attn[b * K_ + k] * w1[((size_t)(k * 64 + o) * 64 + c) * 9 + t];
        W4_2[gid2] = f2bf(acc * gamma[b * 64 + o]);
    } else if (gid < N1 + N2 + 1024) {
        int id2 = gid - N1 - N2;
        int b = id2 >> 7;
        int rest = id2 & 127;
        int o = rest >> 1;
        int which = rest & 1;
        const float* bb = which ? b1 : b2;
        float acc = 0.f;
        #pragma unroll
        for (int k = 0; k < K_; ++k) acc += attn[b * K_ + k] * bb[k * 64 + o];
        float v = acc * gamma[b * 64 + o];
        if (which) bias2[b * 64 + o] = v; else bias1[b * 64 + o] = v;
    }
}

// ---------------------------------------------------------------------------
// Zero halo borders of the padded X1p / Tp buffers.
// ---------------------------------------------------------------------------
__global__ void k_border(unsigned short* __restrict__ X1p, unsigned short* __restrict__ Tp) {
    int gid = blockIdx.x * 256 + threadIdx.x;
    if (gid >= 2 * B_ * 1028 * 8) return;
    int chunk = gid & 7;
    int rest = gid >> 3;
    int p = rest % 1028;
    int rb = rest / 1028;
    int buf = rb & 1, b = rb >> 1;
    int row, col;
    if (p < 258) { row = 0; col = p; }
    else if (p < 516) { row = 257; col = p - 258; }
    else if (p < 772) { row = p - 516 + 1; col = 0; }
    else { row = p - 772 + 1; col = 257; }
    unsigned short* base = (buf ? Tp : X1p) +
        ((size_t)b * PXP_ + (size_t)row * WP_ + col) * 64 + chunk * 8;
    *(short8*)base = (short8){0, 0, 0, 0, 0, 0, 0, 0};
}

// ---------------------------------------------------------------------------
// x [b][64][HW] f32  ->  X1p [b][258][258][64] bf16 (interior only)
// ---------------------------------------------------------------------------
__global__ __launch_bounds__(256) void k_prep(const float* __restrict__ x,
                                              unsigned short* __restrict__ X1p) {
    __shared__ float ls[64][65];
    const int b = blockIdx.y;
    const int px0 = blockIdx.x * 64;
    const int row = px0 >> 8;
    const int col0 = px0 & 255;
    const int t = threadIdx.x;
    for (int e = t; e < 4096; e += 256) {
        int ch = e >> 6, px = e & 63;
        ls[ch][px] = x[((size_t)b * 64 + ch) * HW_ + px0 + px];
    }
    __syncthreads();
    unsigned short* dst = X1p + ((size_t)b * PXP_ + (size_t)(row + 1) * WP_ + col0 + 1) * 64;
    for (int e = t; e < 4096; e += 256) {
        int ch = e & 63, px = e >> 6;
        dst[(size_t)px * 64 + ch] = f2bf(ls[ch][px]);
    }
}

// ---------------------------------------------------------------------------
// Implicit-GEMM conv3x3 via MFMA. Block: 512 thr / 8 waves, 8 img-rows x 32 w
// x 64 o (2 bands share one unified slab). A: slab [10][34][64] bf16 (43.5 KB)
// via async global_load_lds. B: 5-slot x 4KB LDS ring, prefetch distance 4,
// counted vmcnt (never drain-0 mid-loop), raw s_barrier. 64 KB LDS ->
// 2 blocks/CU = 4 waves/SIMD.
// ---------------------------------------------------------------------------
template<int STAGE>
__global__ __launch_bounds__(512, 4) void k_conv(
    const unsigned short* __restrict__ Xp,    // [b][258][258][64] bf16 padded
    const float* __restrict__ x_res,          // stage2 residual [b][o][px]
    const float* __restrict__ par,            // stage1 [b][3][HW]
    const unsigned short* __restrict__ W4,    // [b][NS][4][64][8] bf16
    const float* __restrict__ bias,           // [b][64]
    unsigned short* __restrict__ Tp,          // stage1 out [b][258][258][64] bf16
    float* __restrict__ Fout)                 // stage2 out [b][64][HW] f32
{
    constexpr int NS = (STAGE == 1) ? NS1 : NS2;
    __shared__ short xs[SLABR * SLABW * 64];  // 43520 B (aliased as tl in epilogue)
    __shared__ short bring[5 * 2048];         // 20480 B B-ring (5 slots x 4KB)

    const int tid = threadIdx.x;
    const int l = tid & 63;
    const int wv = tid >> 6;                  // 0..7
    const int r_local = (wv >> 2) * 4 + (wv & 3);   // wave's row in the 8-row tile
    const int b = blockIdx.y;
    // XCD-aware bijective swizzle (256 blocks = 8 XCD x 32)
    const int bswz = (blockIdx.x & 7) * 32 + (blockIdx.x >> 3);
    const int rblk = bswz >> 3;               // 0..31
    const int cblk = bswz & 7;                // 0..7
    const int gh0 = rblk * 8, w0 = cblk * 32;
    const int ln15 = l & 15, g = l >> 4;

    const char* XbP = (const char*)Xp + (size_t)b * PXP_ * 128;
    const unsigned short* Wb = W4 + (size_t)b * (NS * 2048);

    // per-lane par row values (stage1)
    float pvv[3][2];
    if constexpr (STAGE == 1) {
        #pragma unroll
        for (int m = 0; m < 3; ++m)
            #pragma unroll
            for (int mf = 0; mf < 2; ++mf)
                pvv[m][mf] = par[((size_t)b * 3 + m) * HW_ +
                                 (gh0 + r_local) * W_ + w0 + 16 * mf + ln15];
    }

    f32x4 acc[2][4];
    #pragma unroll
    for (int mf = 0; mf < 2; ++mf)
        #pragma unroll
        for (int of = 0; of < 4; ++of)
            acc[mf][of] = (f32x4){0.f, 0.f, 0.f, 0.f};

    // ---- async-stage slab [10 rows][34 px][8 chunks]; swizzled src, linear dest
    #pragma unroll
    for (int it = 0; it < 6; ++it) {
        int tau = tid + it * 512;
        if (tau < SLABR * SLABW * 8) {
            int slot = tau & 7;
            int rest = tau >> 3;
            int px = rest % SLABW;
            int row = rest / SLABW;
            int cb = slot ^ (px & 7);
            gload_lds16(XbP + ((size_t)(gh0 + row) * WP_ + (w0 + px)) * 128 + cb * 16,
                        (char*)xs + (size_t)tau * 16);
        }
    }
    // ---- B stage: 4KB/step by waves 0-3 only (their vmcnt gates the barrier)
    auto stage_b = [&](int s) {
        gload_lds16((const char*)Wb + (size_t)s * 4096 + tid * 16,
                    (char*)bring + (s % 5) * 4096 + tid * 16);
    };
    if (tid < 256) { stage_b(0); stage_b(1); stage_b(2); stage_b(3); }

    // A-frag loader (all call sites have compile-time s)
    auto aload = [&](int s, short8* d) {
        const int t = s >> 1, h = s & 1;
        const int dh = t / 3, dw = t - 3 * dh;
        #pragma unroll
        for (int mf = 0; mf < 2; ++mf) {
            int idx = 16 * mf + ln15 + dw;
            d[mf] = *(const short8*)((const char*)xs +
                     ((r_local + dh) * SLABW + idx) * 128 +
                     ((((h << 2) | g) ^ (idx & 7)) << 4));
        }
    };

    // slab + B0 landed; B1..B3 stay in flight for staging waves
    if (wv < 4) asm volatile("s_waitcnt vmcnt(3)" ::: "memory");
    else        asm volatile("s_waitcnt vmcnt(0)" ::: "memory");
    __builtin_amdgcn_s_barrier();

    short8 aa[2][2];
    aload(0, aa[0]);

    #pragma unroll
    for (int s = 0; s < NS; ++s) {
        // B-frags from ring slot s%5 (contiguous 1KB per of -> conflict-free)
        const char* rbase = (const char*)bring + (s % 5) * 4096 + (size_t)l * 16;
        short8 bf0 = *(const short8*)(rbase);
        short8 bf1 = *(const short8*)(rbase + 1024);
        short8 bf2 = *(const short8*)(rbase + 2048);
        short8 bf3 = *(const short8*)(rbase + 3072);
        if (s + 4 < NS && tid < 256) stage_b(s + 4);   // slot (s+4)%5 == (s-1)%5
        if (s + 1 < NS) {                              // A prefetch (static slab)
            if (STAGE == 2 || s + 1 < 18) aload(s + 1, aa[(s + 1) & 1]);
            else aload(8 + ((s + 1) & 1), aa[(s + 1) & 1]);  // par steps: center tap
        }
        short8 af[2];
        if (STAGE == 1 && s >= 18) {        // par-scaled 1x1 expert steps
            const int m = (s - 18) >> 1;
            #pragma unroll
            for (int mf = 0; mf < 2; ++mf)
                #pragma unroll
                for (int j = 0; j < 8; ++j)
                    af[mf][j] = (short)f2bf(bf2f((unsigned short)aa[s & 1][mf][j]) * pvv[m][mf]);
        } else {
            af[0] = aa[s & 1][0];
            af[1] = aa[s & 1][1];
        }
        #pragma unroll
        for (int mf = 0; mf < 2; ++mf) {
            acc[mf][0] = __builtin_amdgcn_mfma_f32_16x16x32_bf16(af[mf], bf0, acc[mf][0], 0, 0, 0);
            acc[mf][1] = __builtin_amdgcn_mfma_f32_16x16x32_bf16(af[mf], bf1, acc[mf][1], 0, 0, 0);
            acc[mf][2] = __builtin_amdgcn_mfma_f32_16x16x32_bf16(af[mf], bf2, acc[mf][2], 0, 0, 0);
            acc[mf][3] = __builtin_amdgcn_mfma_f32_16x16x32_bf16(af[mf], bf3, acc[mf][3], 0, 0, 0);
        }
        if (s + 1 < NS) {
            // counted wait: B(s+1) landed, newer stages stay in flight
            const int nw = (NS - 2 - s) < 3 ? (NS - 2 - s) : 3;
            if (nw == 3)      asm volatile("s_waitcnt vmcnt(3)" ::: "memory");
            else if (nw == 2) asm volatile("s_waitcnt vmcnt(2)" ::: "memory");
            else if (nw == 1) asm volatile("s_waitcnt vmcnt(1)" ::: "memory");
            else              asm volatile("s_waitcnt vmcnt(0)" ::: "memory");
            __builtin_amdgcn_s_barrier();
        }
    }

    if constexpr (STAGE == 1) {
        // ---- epilogue: assemble 128B lines in slab-aliased LDS, store dwordx4
        __syncthreads();                       // all slab/ring reads done
        unsigned short* tl = (unsigned short*)xs;   // [8 rows][32 px][64 o^swz] = 32 KB
        #pragma unroll
        for (int of = 0; of < 4; ++of) {
            int o = of * 16 + ln15;
            float bi = bias[b * 64 + o];
            #pragma unroll
            for (int mf = 0; mf < 2; ++mf) {
                #pragma unroll
                for (int q = 0; q < 4; ++q) {
                    int px = 16 * mf + 4 * g + q;
                    float v = fmaxf(acc[mf][of][q] + bi, 0.f);
                    tl[r_local * 2048 + px * 64 + (o ^ ((px & 7) << 3))] = f2bf(v);
                }
            }
        }
        __syncthreads();
        #pragma unroll
        for (int it = 0; it < 4; ++it) {
            int tau = tid + it * 512;
            int row = tau >> 8;
            int px = (tau >> 3) & 31;
            int j = tau & 7;
            short8 v = *(const short8*)(tl + row * 2048 + px * 64 + ((j ^ (px & 7)) * 8));
            *(short8*)(Tp + ((size_t)b * PXP_ + (size_t)(gh0 + row + 1) * WP_ +
                             (w0 + 1 + px)) * 64 + j * 8) = v;
        }
    } else {
        // ---- epilogue: residual add + f32x4 out
        const int gh = gh0 + r_local;
        #pragma unroll
        for (int of = 0; of < 4; ++of) {
            int o = of * 16 + ln15;
            float bi = bias[b * 64 + o];
            #pragma unroll
            for (int mf = 0; mf < 2; ++mf) {
                int gw = w0 + 16 * mf + g * 4;
                size_t idx = ((size_t)b * 64 + o) * HW_ + gh * W_ + gw;
                f32x4 xv = *(const f32x4*)(x_res + idx);
                f32x4 ov;
                #pragma unroll
                for (int q = 0; q < 4; ++q) ov[q] = xv[q] + acc[mf][of][q] + bi;
                *(f32x4*)(Fout + idx) = ov;
            }
        }
    }
}

extern "C" void kernel_launch(void* const* d_in, const int* in_sizes, int n_in,
                              void* d_out, int out_size, void* d_ws, size_t ws_size,
                              hipStream_t stream) {
    const float* x     = (const float*)d_in[0];
    const float* attn  = (const float*)d_in[1];
    const float* gamma = (const float*)d_in[2];
    const float* par   = (const float*)d_in[3];
    const float* w1    = (const float*)d_in[4];
    const float* b1    = (const float*)d_in[5];
    const float* w2    = (const float*)d_in[6];
    const float* b2    = (const float*)d_in[7];
    const float* w16   = (const float*)d_in[8];
    const float* w168  = (const float*)d_in[9];
    const float* w88   = (const float*)d_in[10];
    float* out = (float*)d_out;

    char* w = (char*)d_ws;
    unsigned short* W4_1 = (unsigned short*)w;                        // 786432 B
    unsigned short* W4_2 = (unsigned short*)(w + 786432);             // 589824 B
    float* bias1 = (float*)(w + 786432 + 589824);                     // 2048 B
    float* bias2 = (float*)(w + 786432 + 589824 + 2048);              // 2048 B
    unsigned short* X1p = (unsigned short*)(w + 1380352);             // 68161536 B
    unsigned short* Tp  = (unsigned short*)(w + 1380352 + 68161536);  // 68161536 B

    k_combine<<<dim3(2692), dim3(256), 0, stream>>>(attn, gamma, w1, b1, w2, b2,
                                                    w16, w168, w88, W4_1, W4_2, bias1, bias2);
    k_border<<<dim3(514), dim3(256), 0, stream>>>(X1p, Tp);
    k_prep<<<dim3(1024, 8), dim3(256), 0, stream>>>(x, X1p);

    dim3 grid(256, 8);
    k_conv<1><<<grid, dim3(512), 0, stream>>>(X1p, nullptr, par, W4_1, bias1, Tp, nullptr);
    k_conv<2><<<grid, dim3(512), 0, stream>>>(Tp, x, nullptr, W4_2, bias2, nullptr, out);
}

// Round 10
// 186.449 us; speedup vs baseline: 4.2043x; 1.0605x over previous
//
#include <hip/hip_runtime.h>
#include <hip/hip_bf16.h>

typedef __attribute__((ext_vector_type(8))) short short8;
typedef __attribute__((ext_vector_type(4))) float f32x4;

#define B_ 8
#define C_ 64
#define H_ 256
#define W_ 256
#define HW_ 65536
#define K_ 10
#define NS1 24
#define NS2 18
#define HP_ 258
#define WP_ 258
#define PXP_ (HP_*WP_)
#define SLABW 34
#define SLABR 10

static __device__ __forceinline__ unsigned short f2bf(float f) {
    __hip_bfloat16 hb = __float2bfloat16(f);
    return *(unsigned short*)&hb;
}
static __device__ __forceinline__ float bf2f(unsigned short u) {
    unsigned v = ((unsigned)u) << 16;
    float f;
    __builtin_memcpy(&f, &v, 4);
    return f;
}

// async global->LDS 16B (dest = wave-uniform base + lane*16, linear in tau)
static __device__ __forceinline__ void gload_lds16(const void* g, void* l) {
    __builtin_amdgcn_global_load_lds(
        (const __attribute__((address_space(1))) unsigned int*)(unsigned long long)g,
        (__attribute__((address_space(3))) unsigned int*)(unsigned int)(unsigned long long)l,
        16, 0, 0);
}

// ---------------------------------------------------------------------------
// Fragment-ordered, gamma-folded, expert-mixed weights + biases.
// W4_1: [b][24 steps][4 of][64 lane][8] bf16 (0..17 conv taps, 18..23 1x1)
// W4_2: [b][18 steps][4][64][8] bf16
// ---------------------------------------------------------------------------
__global__ void k_combine(const float* __restrict__ attn, const float* __restrict__ gamma,
                          const float* __restrict__ w1, const float* __restrict__ b1,
                          const float* __restrict__ w2, const float* __restrict__ b2,
                          const float* __restrict__ w16, const float* __restrict__ w168,
                          const float* __restrict__ w88,
                          unsigned short* __restrict__ W4_1, unsigned short* __restrict__ W4_2,
                          float* __restrict__ bias1, float* __restrict__ bias2) {
    const int N1 = B_ * NS1 * 2048;
    const int N2 = B_ * NS2 * 2048;
    int gid = blockIdx.x * 256 + threadIdx.x;
    if (gid < N1) {
        int b = gid / (NS1 * 2048);
        int r = gid - b * (NS1 * 2048);
        int s = r >> 11;
        int r2 = r & 2047;
        int of = r2 >> 9, l = (r2 >> 3) & 63, j = r2 & 7;
        int o = of * 16 + (l & 15);
        int g = l >> 4;
        float val;
        if (s < 18) {
            int t = s >> 1, h = s & 1;
            int c = h * 32 + g * 8 + j;
            float acc = 0.f;
            #pragma unroll
            for (int k = 0; k < K_; ++k)
                acc += attn[b * K_ + k] * w2[((size_t)(k * 64 + o) * 64 + c) * 9 + t];
            val = acc * gamma[b * 64 + o];
        } else {
            int e = s - 18;
            int m = e >> 1, h = e & 1;
            int c = h * 32 + g * 8 + j;
            const float* wm = (m == 0) ? w16 : (m == 1 ? w168 : w88);
            val = wm[o * 64 + c];
        }
        W4_1[gid] = f2bf(val);
    } else if (gid < N1 + N2) {
        int gid2 = gid - N1;
        int b = gid2 / (NS2 * 2048);
        int r = gid2 - b * (NS2 * 2048);
        int s = r >> 11;
        int r2 = r & 2047;
        int of = r2 >> 9, l = (r2 >> 3) & 63, j = r2 & 7;
        int o = of * 16 + (l & 15);
        int g = l >> 4;
        int t = s >> 1, h = s & 1;
        int c = h * 32 + g * 8 + j;
        float acc = 0.f;
        #pragma unroll
        for (int k = 0; k < K_; ++k)
            acc += attn[b * K_ + k] * w1[((size_t)(k * 64 + o) * 64 + c) * 9 + t];
        W4_2[gid2] = f2bf(acc * gamma[b * 64 + o]);
    } else if (gid < N1 + N2 + 1024) {
        int id2 = gid - N1 - N2;
        int b = id2 >> 7;
        int rest = id2 & 127;
        int o = rest >> 1;
        int which = rest & 1;
        const float* bb = which ? b1 : b2;
        float acc = 0.f;
        #pragma unroll
        for (int k = 0; k < K_; ++k) acc += attn[b * K_ + k] * bb[k * 64 + o];
        float v = acc * gamma[b * 64 + o];
        if (which) bias2[b * 64 + o] = v; else bias1[b * 64 + o] = v;
    }
}

// ---------------------------------------------------------------------------
// Zero halo borders of the padded X1p / Tp buffers.
// ---------------------------------------------------------------------------
__global__ void k_border(unsigned short* __restrict__ X1p, unsigned short* __restrict__ Tp) {
    int gid = blockIdx.x * 256 + threadIdx.x;
    if (gid >= 2 * B_ * 1028 * 8) return;
    int chunk = gid & 7;
    int rest = gid >> 3;
    int p = rest % 1028;
    int rb = rest / 1028;
    int buf = rb & 1, b = rb >> 1;
    int row, col;
    if (p < 258) { row = 0; col = p; }
    else if (p < 516) { row = 257; col = p - 258; }
    else if (p < 772) { row = p - 516 + 1; col = 0; }
    else { row = p - 772 + 1; col = 257; }
    unsigned short* base = (buf ? Tp : X1p) +
        ((size_t)b * PXP_ + (size_t)row * WP_ + col) * 64 + chunk * 8;
    *(short8*)base = (short8){0, 0, 0, 0, 0, 0, 0, 0};
}

// ---------------------------------------------------------------------------
// x [b][64][HW] f32  ->  X1p [b][258][258][64] bf16 (interior only)
// ---------------------------------------------------------------------------
__global__ __launch_bounds__(256) void k_prep(const float* __restrict__ x,
                                              unsigned short* __restrict__ X1p) {
    __shared__ float ls[64][65];
    const int b = blockIdx.y;
    const int px0 = blockIdx.x * 64;
    const int row = px0 >> 8;
    const int col0 = px0 & 255;
    const int t = threadIdx.x;
    for (int e = t; e < 4096; e += 256) {
        int ch = e >> 6, px = e & 63;
        ls[ch][px] = x[((size_t)b * 64 + ch) * HW_ + px0 + px];
    }
    __syncthreads();
    unsigned short* dst = X1p + ((size_t)b * PXP_ + (size_t)(row + 1) * WP_ + col0 + 1) * 64;
    for (int e = t; e < 4096; e += 256) {
        int ch = e & 63, px = e >> 6;
        dst[(size_t)px * 64 + ch] = f2bf(ls[ch][px]);
    }
}

// ---------------------------------------------------------------------------
// Implicit-GEMM conv3x3 via MFMA. Block: 256 thr / 4 FAT waves.
// Wave owns M=64 px (2 img rows x 32 w), N=64 o -> 16 MFMA per K-step,
// halving LDS bytes per MFMA vs 8-thin-wave layout.
// 2-step phases: 16 ds_read_b128 + 32 MFMA + counted vmcnt(2) + s_barrier.
// A: slab [10][34][64] bf16 (43.5 KB, global_load_lds). B: 6-slot x 4KB ring.
// ---------------------------------------------------------------------------
template<int STAGE>
__global__ __launch_bounds__(256, 2) void k_conv(
    const unsigned short* __restrict__ Xp,    // [b][258][258][64] bf16 padded
    const float* __restrict__ x_res,          // stage2 residual [b][o][px]
    const float* __restrict__ par,            // stage1 [b][3][HW]
    const unsigned short* __restrict__ W4,    // [b][NS][4][64][8] bf16
    const float* __restrict__ bias,           // [b][64]
    unsigned short* __restrict__ Tp,          // stage1 out [b][258][258][64] bf16
    float* __restrict__ Fout)                 // stage2 out [b][64][HW] f32
{
    constexpr int NS = (STAGE == 1) ? NS1 : NS2;
    constexpr int NPH = NS / 2;
    __shared__ short xs[SLABR * SLABW * 64];  // 43520 B (aliased as tl in epilogue)
    __shared__ short bring[6 * 2048];         // 24576 B B-ring (6 slots x 4KB)

    const int tid = threadIdx.x;
    const int l = tid & 63;
    const int wv = tid >> 6;                  // 0..3; wave owns rows 2wv, 2wv+1
    const int b = blockIdx.y;
    // XCD-aware bijective swizzle (256 blocks = 8 XCD x 32)
    const int bswz = (blockIdx.x & 7) * 32 + (blockIdx.x >> 3);
    const int rblk = bswz >> 3;               // 0..31
    const int cblk = bswz & 7;                // 0..7
    const int gh0 = rblk * 8, w0 = cblk * 32;
    const int ln15 = l & 15, g = l >> 4;

    const char* XbP = (const char*)Xp + (size_t)b * PXP_ * 128;
    const unsigned short* Wb = W4 + (size_t)b * (NS * 2048);

    // per-lane par values: A-frag mf covers img row gh0+2wv+(mf>>1), px w0+16(mf&1)+ln15
    float pvv[3][4];
    if constexpr (STAGE == 1) {
        #pragma unroll
        for (int m = 0; m < 3; ++m)
            #pragma unroll
            for (int mf = 0; mf < 4; ++mf)
                pvv[m][mf] = par[((size_t)b * 3 + m) * HW_ +
                                 (gh0 + 2 * wv + (mf >> 1)) * W_ + w0 + 16 * (mf & 1) + ln15];
    }

    f32x4 acc[4][4];
    #pragma unroll
    for (int mf = 0; mf < 4; ++mf)
        #pragma unroll
        for (int of = 0; of < 4; ++of)
            acc[mf][of] = (f32x4){0.f, 0.f, 0.f, 0.f};

    // ---- async-stage slab [10 rows][34 px][8 chunks]; swizzled src, linear dest
    #pragma unroll
    for (int it = 0; it < 11; ++it) {
        int tau = tid + it * 256;
        if (tau < SLABR * SLABW * 8) {
            int slot = tau & 7;
            int rest = tau >> 3;
            int px = rest % SLABW;
            int row = rest / SLABW;
            int cb = slot ^ (px & 7);
            gload_lds16(XbP + ((size_t)(gh0 + row) * WP_ + (w0 + px)) * 128 + cb * 16,
                        (char*)xs + (size_t)tau * 16);
        }
    }
    // ---- B stage: 4KB/step, 1 gload per thread
    auto stage_b = [&](int s) {
        gload_lds16((const char*)Wb + (size_t)s * 4096 + tid * 16,
                    (char*)bring + (s % 6) * 4096 + tid * 16);
    };
    stage_b(0); stage_b(1); stage_b(2); stage_b(3);

    // A-frag loader (call sites fully unrolled -> s compile-time)
    auto aload = [&](int s, short8* d) {
        int dh, dw;
        const int h = s & 1;
        if (STAGE == 1 && s >= 18) { dh = 1; dw = 1; }
        else { const int t = s >> 1; dh = t / 3; dw = t - 3 * dh; }
        #pragma unroll
        for (int mf = 0; mf < 4; ++mf) {
            int idx = 16 * (mf & 1) + ln15 + dw;
            int row = 2 * wv + (mf >> 1) + dh;
            d[mf] = *(const short8*)((const char*)xs + (row * SLABW + idx) * 128 +
                                     ((((h << 2) | g) ^ (idx & 7)) << 4));
        }
    };

    // slab + B0,B1 landed; keep B2,B3 in flight
    asm volatile("s_waitcnt vmcnt(2)" ::: "memory");
    __builtin_amdgcn_s_barrier();

    #pragma unroll
    for (int p = 0; p < NPH; ++p) {
        const int s0 = 2 * p, s1 = 2 * p + 1;
        // ---- B frags for both steps (contiguous 1KB per of -> conflict-free)
        const char* r0 = (const char*)bring + (s0 % 6) * 4096 + (size_t)l * 16;
        const char* r1 = (const char*)bring + (s1 % 6) * 4096 + (size_t)l * 16;
        short8 b0[4], b1[4];
        #pragma unroll
        for (int of = 0; of < 4; ++of) {
            b0[of] = *(const short8*)(r0 + of * 1024);
            b1[of] = *(const short8*)(r1 + of * 1024);
        }
        // ---- A frags for both steps
        short8 a0[4], a1[4];
        aload(s0, a0);
        aload(s1, a1);
        // ---- stage 2 steps ahead (slots (2p+4)%6,(2p+5)%6 freed in phase p-1)
        if (s0 + 4 < NS) stage_b(s0 + 4);
        if (s1 + 4 < NS) stage_b(s1 + 4);
        // ---- par scaling for stage1 expert steps
        if (STAGE == 1 && s0 >= 18) {
            const int m = (s0 - 18) >> 1;
            #pragma unroll
            for (int mf = 0; mf < 4; ++mf)
                #pragma unroll
                for (int j = 0; j < 8; ++j) {
                    a0[mf][j] = (short)f2bf(bf2f((unsigned short)a0[mf][j]) * pvv[m][mf]);
                    a1[mf][j] = (short)f2bf(bf2f((unsigned short)a1[mf][j]) * pvv[m][mf]);
                }
        }
        // ---- 32 MFMA (16 indep chains of 2)
        __builtin_amdgcn_s_setprio(1);
        #pragma unroll
        for (int mf = 0; mf < 4; ++mf)
            #pragma unroll
            for (int of = 0; of < 4; ++of)
                acc[mf][of] = __builtin_amdgcn_mfma_f32_16x16x32_bf16(
                    a0[mf], b0[of], acc[mf][of], 0, 0, 0);
        #pragma unroll
        for (int mf = 0; mf < 4; ++mf)
            #pragma unroll
            for (int of = 0; of < 4; ++of)
                acc[mf][of] = __builtin_amdgcn_mfma_f32_16x16x32_bf16(
                    a1[mf], b1[of], acc[mf][of], 0, 0, 0);
        __builtin_amdgcn_s_setprio(0);
        if (p + 1 < NPH) {
            // counted wait: next phase's 2 steps landed, newest 2 stay in flight
            const int rem = NS - (2 * p + 2);
            const int nw = (rem >= 4) ? 2 : (rem - 2 > 0 ? rem - 2 : 0);
            if (nw == 2)      asm volatile("s_waitcnt vmcnt(2)" ::: "memory");
            else if (nw == 1) asm volatile("s_waitcnt vmcnt(1)" ::: "memory");
            else              asm volatile("s_waitcnt vmcnt(0)" ::: "memory");
            __builtin_amdgcn_s_barrier();
        }
    }

    if constexpr (STAGE == 1) {
        // ---- epilogue: assemble 128B lines in slab-aliased LDS, store dwordx4
        __syncthreads();                       // all slab/ring reads done
        unsigned short* tl = (unsigned short*)xs;   // [8 rows][32 px][64 o^swz] = 32 KB
        #pragma unroll
        for (int of = 0; of < 4; ++of) {
            int o = of * 16 + ln15;
            float bi = bias[b * 64 + o];
            #pragma unroll
            for (int mf = 0; mf < 4; ++mf) {
                int row_local = 2 * wv + (mf >> 1);
                #pragma unroll
                for (int q = 0; q < 4; ++q) {
                    int px = 16 * (mf & 1) + 4 * g + q;
                    float v = fmaxf(acc[mf][of][q] + bi, 0.f);
                    tl[row_local * 2048 + px * 64 + (o ^ ((px & 7) << 3))] = f2bf(v);
                }
            }
        }
        __syncthreads();
        #pragma unroll
        for (int it = 0; it < 8; ++it) {
            int tau = tid + it * 256;
            int row = tau >> 8;
            int px = (tau >> 3) & 31;
            int j = tau & 7;
            short8 v = *(const short8*)(tl + row * 2048 + px * 64 + ((j ^ (px & 7)) * 8));
            *(short8*)(Tp + ((size_t)b * PXP_ + (size_t)(gh0 + row + 1) * WP_ +
                             (w0 + 1 + px)) * 64 + j * 8) = v;
        }
    } else {
        // ---- epilogue: residual add + f32x4 out
        #pragma unroll
        for (int of = 0; of < 4; ++of) {
            int o = of * 16 + ln15;
            float bi = bias[b * 64 + o];
            #pragma unroll
            for (int mf = 0; mf < 4; ++mf) {
                int gh = gh0 + 2 * wv + (mf >> 1);
                int gw = w0 + 16 * (mf & 1) + g * 4;
                size_t idx = ((size_t)b * 64 + o) * HW_ + gh * W_ + gw;
                f32x4 xv = *(const f32x4*)(x_res + idx);
                f32x4 ov;
                #pragma unroll
                for (int q = 0; q < 4; ++q) ov[q] = xv[q] + acc[mf][of][q] + bi;
                *(f32x4*)(Fout + idx) = ov;
            }
        }
    }
}

extern "C" void kernel_launch(void* const* d_in, const int* in_sizes, int n_in,
                              void* d_out, int out_size, void* d_ws, size_t ws_size,
                              hipStream_t stream) {
    const float* x     = (const float*)d_in[0];
    const float* attn  = (const float*)d_in[1];
    const float* gamma = (const float*)d_in[2];
    const float* par   = (const float*)d_in[3];
    const float* w1    = (const float*)d_in[4];
    const float* b1    = (const float*)d_in[5];
    const float* w2    = (const float*)d_in[6];
    const float* b2    = (const float*)d_in[7];
    const float* w16   = (const float*)d_in[8];
    const float* w168  = (const float*)d_in[9];
    const float* w88   = (const float*)d_in[10];
    float* out = (float*)d_out;

    char* w = (char*)d_ws;
    unsigned short* W4_1 = (unsigned short*)w;                        // 786432 B
    unsigned short* W4_2 = (unsigned short*)(w + 786432);             // 589824 B
    float* bias1 = (float*)(w + 786432 + 589824);                     // 2048 B
    float* bias2 = (float*)(w + 786432 + 589824 + 2048);              // 2048 B
    unsigned short* X1p = (unsigned short*)(w + 1380352);             // 68161536 B
    unsigned short* Tp  = (unsigned short*)(w + 1380352 + 68161536);  // 68161536 B

    k_combine<<<dim3(2692), dim3(256), 0, stream>>>(attn, gamma, w1, b1, w2, b2,
                                                    w16, w168, w88, W4_1, W4_2, bias1, bias2);
    k_border<<<dim3(514), dim3(256), 0, stream>>>(X1p, Tp);
    k_prep<<<dim3(1024, 8), dim3(256), 0, stream>>>(x, X1p);

    dim3 grid(256, 8);
    k_conv<1><<<grid, dim3(256), 0, stream>>>(X1p, nullptr, par, W4_1, bias1, Tp, nullptr);
    k_conv<2><<<grid, dim3(256), 0, stream>>>(Tp, x, nullptr, W4_2, bias2, nullptr, out);
}